// Round 1
// baseline (5391.848 us; speedup 1.0000x reference)
//
#include <hip/hip_runtime.h>
#include <hip/hip_bf16.h>

// Problem constants (from reference)
constexpr int NN = 100000;            // nodes
constexpr int NE = 1600000;           // edges (without self loops)
constexpr int EP = NE + NN;           // edges incl. self loops = 1,700,000
constexpr float NEG = 0.2f;           // leaky relu slope

__device__ __forceinline__ float elu_f(float x) { return x > 0.f ? x : __expf(x) - 1.f; }

// ---------------- GEMM: H[N,M] = X[N,K] @ W[K,M] ----------------
// Each thread computes 4 consecutive output cols for one node.
template<int K, int M>
__global__ __launch_bounds__(256) void gemm_kernel(const float* __restrict__ X,
                                                   const float* __restrict__ W,
                                                   float* __restrict__ H) {
    constexpr int TPN = M / 4;          // threads per node
    constexpr int NPB = 256 / TPN;      // nodes per block
    int tid = threadIdx.x;
    int node = blockIdx.x * NPB + tid / TPN;
    int c0 = (tid % TPN) * 4;
    if (node >= NN) return;
    const float* xr = X + (size_t)node * K;
    float4 acc = make_float4(0.f, 0.f, 0.f, 0.f);
#pragma unroll 4
    for (int k = 0; k < K; k += 4) {
        const float4 xv = *reinterpret_cast<const float4*>(xr + k);
        const float4 w0 = *reinterpret_cast<const float4*>(W + (size_t)(k + 0) * M + c0);
        const float4 w1 = *reinterpret_cast<const float4*>(W + (size_t)(k + 1) * M + c0);
        const float4 w2 = *reinterpret_cast<const float4*>(W + (size_t)(k + 2) * M + c0);
        const float4 w3 = *reinterpret_cast<const float4*>(W + (size_t)(k + 3) * M + c0);
        acc.x += xv.x * w0.x + xv.y * w1.x + xv.z * w2.x + xv.w * w3.x;
        acc.y += xv.x * w0.y + xv.y * w1.y + xv.z * w2.y + xv.w * w3.y;
        acc.z += xv.x * w0.z + xv.y * w1.z + xv.z * w2.z + xv.w * w3.z;
        acc.w += xv.x * w0.w + xv.y * w1.w + xv.z * w2.w + xv.w * w3.w;
    }
    *reinterpret_cast<float4*>(H + (size_t)node * M + c0) = acc;
}

// ---------------- per-node attention coefficients ----------------
// as[n,h] = dot(Hm[n,h,:], a_src[h,:]); ad likewise.
template<int H, int C>
__global__ void alpha_kernel(const float* __restrict__ Hm, const float* __restrict__ a_src,
                             const float* __restrict__ a_dst,
                             float* __restrict__ as, float* __restrict__ ad) {
    int idx = blockIdx.x * blockDim.x + threadIdx.x;   // node*H + h
    if (idx >= NN * H) return;
    int node = idx / H, h = idx % H;
    const float* hr = Hm + (size_t)node * (H * C) + h * C;
    const float* sr = a_src + h * C;
    const float* dr = a_dst + h * C;
    float s = 0.f, d = 0.f;
#pragma unroll
    for (int c = 0; c < C; c += 4) {
        float4 hv = *reinterpret_cast<const float4*>(hr + c);
        float4 sv = *reinterpret_cast<const float4*>(sr + c);
        float4 dv = *reinterpret_cast<const float4*>(dr + c);
        s += hv.x * sv.x + hv.y * sv.y + hv.z * sv.z + hv.w * sv.w;
        d += hv.x * dv.x + hv.y * dv.y + hv.z * dv.z + hv.w * dv.w;
    }
    as[idx] = s; ad[idx] = d;
}

// ---------------- edge pass: w = exp(leakyrelu(as[src]+ad[dst])), denom[dst] += w ----------------
template<int H>
__global__ void edge_kernel(const int* __restrict__ ei, const float* __restrict__ as,
                            const float* __restrict__ ad,
                            float* __restrict__ wbuf, float* __restrict__ denom) {
    int i = blockIdx.x * blockDim.x + threadIdx.x;
    if (i >= EP) return;
    int s, d;
    if (i < NE) { s = ei[i]; d = ei[NE + i]; }
    else        { s = d = i - NE; }
#pragma unroll
    for (int h = 0; h < H; ++h) {
        float e = as[s * H + h] + ad[d * H + h];
        e = e > 0.f ? e : NEG * e;
        float w = __expf(e);
        wbuf[(size_t)i * H + h] = w;
        atomicAdd(&denom[d * H + h], w);
    }
}

// ---------------- aggregation: out[dst, :] += alpha * h[src, :] ----------------
template<int H, int C>
__global__ __launch_bounds__(256) void agg_kernel(const int* __restrict__ ei,
                                                  const float* __restrict__ wbuf,
                                                  const float* __restrict__ denom,
                                                  const float* __restrict__ hsrc,
                                                  float* __restrict__ outd) {
    constexpr int M = H * C;
    constexpr int TPE = M / 4;          // threads per edge
    int gid = blockIdx.x * 256 + threadIdx.x;
    int i = gid / TPE;
    int part = gid % TPE;
    if (i >= EP) return;
    int s, d;
    if (i < NE) { s = ei[i]; d = ei[NE + i]; }
    else        { s = d = i - NE; }
    int c0 = part * 4;
    int h = c0 / C;
    float alpha = wbuf[(size_t)i * H + h] / (denom[d * H + h] + 1e-16f);
    float4 hv = *reinterpret_cast<const float4*>(hsrc + (size_t)s * M + c0);
    float* o = outd + (size_t)d * M + c0;
    atomicAdd(o + 0, alpha * hv.x);
    atomicAdd(o + 1, alpha * hv.y);
    atomicAdd(o + 2, alpha * hv.z);
    atomicAdd(o + 3, alpha * hv.w);
}

// ---------------- elementwise: X = elu(X + b) ----------------
template<int M>
__global__ void elu_bias_kernel(float* __restrict__ X, const float* __restrict__ b) {
    int idx = blockIdx.x * blockDim.x + threadIdx.x;
    if (idx >= NN * (M / 4)) return;
    int c0 = (idx * 4) % M;
    float4 v = *reinterpret_cast<float4*>(X + (size_t)idx * 4);
    v.x = elu_f(v.x + b[c0 + 0]);
    v.y = elu_f(v.y + b[c0 + 1]);
    v.z = elu_f(v.z + b[c0 + 2]);
    v.w = elu_f(v.w + b[c0 + 3]);
    *reinterpret_cast<float4*>(X + (size_t)idx * 4) = v;
}

// ---------------- MLP head + mean pool ----------------
// out2[n,64] (+b2) -> elu(@Wl1+bl1) -> @Wl2+bl2 -> sum over nodes into pool[64]
__global__ __launch_bounds__(256) void mlp_pool_kernel(const float* __restrict__ out2,
                                                       const float* __restrict__ b2,
                                                       const float* __restrict__ Wl1,
                                                       const float* __restrict__ bl1,
                                                       const float* __restrict__ Wl2,
                                                       const float* __restrict__ bl2,
                                                       float* __restrict__ pool) {
    __shared__ float sW1[64 * 64];
    __shared__ float sW2[64 * 64];
    __shared__ float sv[4][64];
    __shared__ float st[4][64];
    __shared__ float sacc[256];
    int tid = threadIdx.x;
    for (int i = tid; i < 64 * 64; i += 256) { sW1[i] = Wl1[i]; sW2[i] = Wl2[i]; }
    __syncthreads();
    int ln = tid / 64, c = tid % 64;
    float bl1c = bl1[c], bl2c = bl2[c], b2c = b2[c];
    float acc = 0.f;
    for (int base = blockIdx.x * 4; base < NN; base += gridDim.x * 4) {
        int node = base + ln;
        float v = 0.f;
        if (node < NN) v = out2[(size_t)node * 64 + c] + b2c;
        sv[ln][c] = v;
        __syncthreads();
        float t = bl1c;
#pragma unroll
        for (int k = 0; k < 64; ++k) t += sv[ln][k] * sW1[k * 64 + c];
        t = t > 0.f ? t : __expf(t) - 1.f;
        st[ln][c] = t;
        __syncthreads();
        float o = bl2c;
#pragma unroll
        for (int k = 0; k < 64; ++k) o += st[ln][k] * sW2[k * 64 + c];
        if (node < NN) acc += o;
    }
    sacc[tid] = acc;
    __syncthreads();
    if (tid < 64) {
        float r = sacc[tid] + sacc[64 + tid] + sacc[128 + tid] + sacc[192 + tid];
        atomicAdd(&pool[tid], r);
    }
}

__global__ void finalize_kernel(const float* __restrict__ pool, float* __restrict__ out) {
    int c = threadIdx.x;
    if (c < 64) out[c] = pool[c] * (1.0f / NN);
}

extern "C" void kernel_launch(void* const* d_in, const int* in_sizes, int n_in,
                              void* d_out, int out_size, void* d_ws, size_t ws_size,
                              hipStream_t stream) {
    const float* x      = (const float*)d_in[0];
    const int*   ei     = (const int*)d_in[1];
    const float* W1     = (const float*)d_in[2];
    const float* a_src1 = (const float*)d_in[3];
    const float* a_dst1 = (const float*)d_in[4];
    const float* b1     = (const float*)d_in[5];
    const float* W2     = (const float*)d_in[6];
    const float* a_src2 = (const float*)d_in[7];
    const float* a_dst2 = (const float*)d_in[8];
    const float* b2     = (const float*)d_in[9];
    const float* Wl1    = (const float*)d_in[10];
    const float* bl1    = (const float*)d_in[11];
    const float* Wl2    = (const float*)d_in[12];
    const float* bl2    = (const float*)d_in[13];
    float* out = (float*)d_out;

    float* ws = (float*)d_ws;
    size_t o = 0;
    float* h1   = ws + o; o += (size_t)NN * 128;   // [N,2,64]
    float* out1 = ws + o; o += (size_t)NN * 128;   // layer1 aggregate
    float* h2   = ws + o; o += (size_t)NN * 64;    // layer2 transformed feats
    float* wbuf = ws + o; o += (size_t)EP * 2;     // edge exp weights (layer2 reuses first EP)
    float* as1  = ws + o; o += NN * 2;
    float* ad1  = ws + o; o += NN * 2;
    float* den1 = ws + o; o += NN * 2;
    float* as2  = ws + o; o += NN;
    float* ad2  = ws + o; o += NN;
    float* den2 = ws + o; o += NN;
    float* pool = ws + o; o += 64;
    float* out2 = h1;   // reuse: h1 dead after layer-1 aggregation

    // ---- layer 1 ----
    hipMemsetAsync(out1, 0, (size_t)NN * 128 * sizeof(float), stream);
    hipMemsetAsync(den1, 0, (size_t)NN * 2 * sizeof(float), stream);
    gemm_kernel<256, 128><<<(NN + 7) / 8, 256, 0, stream>>>(x, W1, h1);
    alpha_kernel<2, 64><<<(NN * 2 + 255) / 256, 256, 0, stream>>>(h1, a_src1, a_dst1, as1, ad1);
    edge_kernel<2><<<(EP + 255) / 256, 256, 0, stream>>>(ei, as1, ad1, wbuf, den1);
    agg_kernel<2, 64><<<(EP * 32 + 255) / 256, 256, 0, stream>>>(ei, wbuf, den1, h1, out1);
    elu_bias_kernel<128><<<(NN * 32 + 255) / 256, 256, 0, stream>>>(out1, b1);

    // ---- layer 2 ----
    gemm_kernel<128, 64><<<(NN + 15) / 16, 256, 0, stream>>>(out1, W2, h2);
    alpha_kernel<1, 64><<<(NN + 255) / 256, 256, 0, stream>>>(h2, a_src2, a_dst2, as2, ad2);
    hipMemsetAsync(out2, 0, (size_t)NN * 64 * sizeof(float), stream);   // after h1 last use
    hipMemsetAsync(den2, 0, (size_t)NN * sizeof(float), stream);
    hipMemsetAsync(pool, 0, 64 * sizeof(float), stream);
    edge_kernel<1><<<(EP + 255) / 256, 256, 0, stream>>>(ei, as2, ad2, wbuf, den2);
    agg_kernel<1, 64><<<(EP * 16 + 255) / 256, 256, 0, stream>>>(ei, wbuf, den2, h2, out2);

    // ---- MLP head + global mean pool ----
    mlp_pool_kernel<<<2048, 256, 0, stream>>>(out2, b2, Wl1, bl1, Wl2, bl2, pool);
    finalize_kernel<<<1, 64, 0, stream>>>(pool, out);
}

// Round 11
// 1386.275 us; speedup vs baseline: 3.8895x; 3.8895x over previous
//
#include <hip/hip_runtime.h>
#include <hip/hip_bf16.h>

constexpr int NN = 100000;            // nodes
constexpr int NE = 1600000;           // edges (without self loops)
constexpr int EP = NE + NN;           // edges incl. self loops
constexpr float NEG = 0.2f;           // leaky relu slope

__device__ __forceinline__ float elu_f(float x) { return x > 0.f ? x : __expf(x) - 1.f; }

// ---------------- GEMM: H[N,M] = X[N,K] @ W[K,M] ----------------
template<int K, int M>
__global__ __launch_bounds__(256) void gemm_kernel(const float* __restrict__ X,
                                                   const float* __restrict__ W,
                                                   float* __restrict__ H) {
    constexpr int TPN = M / 4;          // threads per node
    constexpr int NPB = 256 / TPN;      // nodes per block
    int tid = threadIdx.x;
    int node = blockIdx.x * NPB + tid / TPN;
    int c0 = (tid % TPN) * 4;
    if (node >= NN) return;
    const float* xr = X + (size_t)node * K;
    float4 acc = make_float4(0.f, 0.f, 0.f, 0.f);
#pragma unroll 4
    for (int k = 0; k < K; k += 4) {
        const float4 xv = *reinterpret_cast<const float4*>(xr + k);
        const float4 w0 = *reinterpret_cast<const float4*>(W + (size_t)(k + 0) * M + c0);
        const float4 w1 = *reinterpret_cast<const float4*>(W + (size_t)(k + 1) * M + c0);
        const float4 w2 = *reinterpret_cast<const float4*>(W + (size_t)(k + 2) * M + c0);
        const float4 w3 = *reinterpret_cast<const float4*>(W + (size_t)(k + 3) * M + c0);
        acc.x += xv.x * w0.x + xv.y * w1.x + xv.z * w2.x + xv.w * w3.x;
        acc.y += xv.x * w0.y + xv.y * w1.y + xv.z * w2.y + xv.w * w3.y;
        acc.z += xv.x * w0.z + xv.y * w1.z + xv.z * w2.z + xv.w * w3.z;
        acc.w += xv.x * w0.w + xv.y * w1.w + xv.z * w2.w + xv.w * w3.w;
    }
    *reinterpret_cast<float4*>(H + (size_t)node * M + c0) = acc;
}

// ---------------- per-node attention coefficients ----------------
template<int H, int C>
__global__ void alpha_kernel(const float* __restrict__ Hm, const float* __restrict__ a_src,
                             const float* __restrict__ a_dst,
                             float* __restrict__ as, float* __restrict__ ad) {
    int idx = blockIdx.x * blockDim.x + threadIdx.x;   // node*H + h
    if (idx >= NN * H) return;
    int node = idx / H, h = idx % H;
    const float* hr = Hm + (size_t)node * (H * C) + h * C;
    const float* sr = a_src + h * C;
    const float* dr = a_dst + h * C;
    float s = 0.f, d = 0.f;
#pragma unroll
    for (int c = 0; c < C; c += 4) {
        float4 hv = *reinterpret_cast<const float4*>(hr + c);
        float4 sv = *reinterpret_cast<const float4*>(sr + c);
        float4 dv = *reinterpret_cast<const float4*>(dr + c);
        s += hv.x * sv.x + hv.y * sv.y + hv.z * sv.z + hv.w * sv.w;
        d += hv.x * dv.x + hv.y * dv.y + hv.z * dv.z + hv.w * dv.w;
    }
    as[idx] = s; ad[idx] = d;
}

// ================= CSR build (by destination) =================
__global__ void count_deg_kernel(const int* __restrict__ ei, int* __restrict__ deg) {
    int i = blockIdx.x * blockDim.x + threadIdx.x;
    if (i >= EP) return;
    int d = (i < NE) ? ei[NE + i] : (i - NE);
    atomicAdd(&deg[d], 1);
}

// block-hierarchical exclusive scan over deg[NN] -> row_ptr (partial, pre-offset)
__global__ __launch_bounds__(256) void scan1_kernel(const int* __restrict__ deg,
                                                    int* __restrict__ excl,
                                                    int* __restrict__ partials) {
    __shared__ int ts[256];
    int tid = threadIdx.x;
    int idx0 = blockIdx.x * 1024 + tid * 4;
    int v0 = (idx0 + 0 < NN) ? deg[idx0 + 0] : 0;
    int v1 = (idx0 + 1 < NN) ? deg[idx0 + 1] : 0;
    int v2 = (idx0 + 2 < NN) ? deg[idx0 + 2] : 0;
    int v3 = (idx0 + 3 < NN) ? deg[idx0 + 3] : 0;
    int s0 = v0, s1 = s0 + v1, s2 = s1 + v2, s3 = s2 + v3;
    ts[tid] = s3;
    __syncthreads();
    for (int off = 1; off < 256; off <<= 1) {
        int t = (tid >= off) ? ts[tid - off] : 0;
        __syncthreads();
        ts[tid] += t;
        __syncthreads();
    }
    int te = ts[tid] - s3;   // exclusive offset of this thread within block
    if (idx0 + 0 < NN) excl[idx0 + 0] = te;
    if (idx0 + 1 < NN) excl[idx0 + 1] = te + s0;
    if (idx0 + 2 < NN) excl[idx0 + 2] = te + s1;
    if (idx0 + 3 < NN) excl[idx0 + 3] = te + s2;
    if (tid == 255) partials[blockIdx.x] = ts[255];
}

__global__ void scan2_kernel(int* __restrict__ partials, int nb) {
    if (threadIdx.x == 0 && blockIdx.x == 0) {
        int run = 0;
        for (int i = 0; i < nb; ++i) { int t = partials[i]; partials[i] = run; run += t; }
    }
}

__global__ void scan3_kernel(int* __restrict__ row_ptr, int* __restrict__ cursor,
                             const int* __restrict__ partials) {
    int i = blockIdx.x * blockDim.x + threadIdx.x;
    if (i == 0) row_ptr[NN] = EP;
    if (i >= NN) return;
    int v = row_ptr[i] + partials[i >> 10];
    row_ptr[i] = v;
    cursor[i] = v;
}

__global__ void scatter_kernel(const int* __restrict__ ei, int* __restrict__ cursor,
                               int* __restrict__ csr_src) {
    int i = blockIdx.x * blockDim.x + threadIdx.x;
    if (i >= EP) return;
    int s, d;
    if (i < NE) { s = ei[i]; d = ei[NE + i]; }
    else        { s = d = i - NE; }
    int pos = atomicAdd(&cursor[d], 1);
    csr_src[pos] = s;
}

// ================= gather aggregation (no atomics) =================
// Layer 1: H=2, C=64. One wave per node; lane handles channels 2*lane, 2*lane+1.
__global__ __launch_bounds__(256) void agg1_kernel(const int* __restrict__ rp,
                                                   const int* __restrict__ cs,
                                                   const float* __restrict__ h1,
                                                   const float* __restrict__ as,
                                                   const float* __restrict__ ad,
                                                   const float* __restrict__ b,
                                                   float* __restrict__ out1) {
    int wid = threadIdx.x >> 6, lane = threadIdx.x & 63;
    int node = blockIdx.x * 4 + wid;
    if (node >= NN) return;
    int h = lane >> 5;           // head for channels 2*lane, 2*lane+1
    int c0 = 2 * lane;
    float adv = ad[2 * node + h];
    float accx = 0.f, accy = 0.f, wsum = 0.f;
    int beg = rp[node], end = rp[node + 1];
    for (int j = beg; j < end; ++j) {
        int s = cs[j];
        float2 asv = *reinterpret_cast<const float2*>(as + 2 * s);
        float e = (h ? asv.y : asv.x) + adv;
        e = e > 0.f ? e : NEG * e;
        float w = __expf(e);
        float2 hv = *reinterpret_cast<const float2*>(h1 + (size_t)s * 128 + c0);
        accx += w * hv.x; accy += w * hv.y; wsum += w;
    }
    float inv = 1.f / (wsum + 1e-16f);
    float2 o;
    o.x = elu_f(accx * inv + b[c0 + 0]);
    o.y = elu_f(accy * inv + b[c0 + 1]);
    *reinterpret_cast<float2*>(out1 + (size_t)node * 128 + c0) = o;
}

// Layer 2: H=1, C=64. One wave per node; lane handles channel `lane`. +b2 fused.
__global__ __launch_bounds__(256) void agg2_kernel(const int* __restrict__ rp,
                                                   const int* __restrict__ cs,
                                                   const float* __restrict__ h2,
                                                   const float* __restrict__ as,
                                                   const float* __restrict__ ad,
                                                   const float* __restrict__ b2,
                                                   float* __restrict__ out2) {
    int wid = threadIdx.x >> 6, lane = threadIdx.x & 63;
    int node = blockIdx.x * 4 + wid;
    if (node >= NN) return;
    float adv = ad[node];
    float acc = 0.f, wsum = 0.f;
    int beg = rp[node], end = rp[node + 1];
    for (int j = beg; j < end; ++j) {
        int s = cs[j];
        float e = as[s] + adv;
        e = e > 0.f ? e : NEG * e;
        float w = __expf(e);
        acc += w * h2[(size_t)s * 64 + lane];
        wsum += w;
    }
    out2[(size_t)node * 64 + lane] = acc / (wsum + 1e-16f) + b2[lane];
}

// ---------------- MLP head + mean pool (b2 already fused into out2) ----------------
__global__ __launch_bounds__(256) void mlp_pool_kernel(const float* __restrict__ out2,
                                                       const float* __restrict__ Wl1,
                                                       const float* __restrict__ bl1,
                                                       const float* __restrict__ Wl2,
                                                       const float* __restrict__ bl2,
                                                       float* __restrict__ pool) {
    __shared__ float sW1[64 * 64];
    __shared__ float sW2[64 * 64];
    __shared__ float sv[4][64];
    __shared__ float st[4][64];
    __shared__ float sacc[256];
    int tid = threadIdx.x;
    for (int i = tid; i < 64 * 64; i += 256) { sW1[i] = Wl1[i]; sW2[i] = Wl2[i]; }
    __syncthreads();
    int ln = tid / 64, c = tid % 64;
    float bl1c = bl1[c], bl2c = bl2[c];
    float acc = 0.f;
    for (int base = blockIdx.x * 4; base < NN; base += gridDim.x * 4) {
        int node = base + ln;
        float v = 0.f;
        if (node < NN) v = out2[(size_t)node * 64 + c];
        sv[ln][c] = v;
        __syncthreads();
        float t = bl1c;
#pragma unroll
        for (int k = 0; k < 64; ++k) t += sv[ln][k] * sW1[k * 64 + c];
        t = t > 0.f ? t : __expf(t) - 1.f;
        st[ln][c] = t;
        __syncthreads();
        float o = bl2c;
#pragma unroll
        for (int k = 0; k < 64; ++k) o += st[ln][k] * sW2[k * 64 + c];
        if (node < NN) acc += o;
        __syncthreads();
    }
    sacc[tid] = acc;
    __syncthreads();
    if (tid < 64) {
        float r = sacc[tid] + sacc[64 + tid] + sacc[128 + tid] + sacc[192 + tid];
        atomicAdd(&pool[tid], r);
    }
}

__global__ void finalize_kernel(const float* __restrict__ pool, float* __restrict__ out) {
    int c = threadIdx.x;
    if (c < 64) out[c] = pool[c] * (1.0f / NN);
}

extern "C" void kernel_launch(void* const* d_in, const int* in_sizes, int n_in,
                              void* d_out, int out_size, void* d_ws, size_t ws_size,
                              hipStream_t stream) {
    const float* x      = (const float*)d_in[0];
    const int*   ei     = (const int*)d_in[1];
    const float* W1     = (const float*)d_in[2];
    const float* a_src1 = (const float*)d_in[3];
    const float* a_dst1 = (const float*)d_in[4];
    const float* b1     = (const float*)d_in[5];
    const float* W2     = (const float*)d_in[6];
    const float* a_src2 = (const float*)d_in[7];
    const float* a_dst2 = (const float*)d_in[8];
    const float* b2     = (const float*)d_in[9];
    const float* Wl1    = (const float*)d_in[10];
    const float* bl1    = (const float*)d_in[11];
    const float* Wl2    = (const float*)d_in[12];
    const float* bl2    = (const float*)d_in[13];
    float* out = (float*)d_out;

    float* ws = (float*)d_ws;
    size_t o = 0;
    float* h1      = ws + o; o += (size_t)NN * 128;   // [N,2,64]
    float* out1    = ws + o; o += (size_t)NN * 128;
    float* h2      = ws + o; o += (size_t)NN * 64;
    float* as1     = ws + o; o += NN * 2;
    float* ad1     = ws + o; o += NN * 2;
    float* as2     = ws + o; o += NN;
    float* ad2     = ws + o; o += NN;
    float* pool    = ws + o; o += 64;
    int* deg       = (int*)(ws + o); o += NN;
    int* row_ptr   = (int*)(ws + o); o += NN + 2;
    int* cursor    = (int*)(ws + o); o += NN;
    int* partials  = (int*)(ws + o); o += 128;
    int* csr_src   = (int*)(ws + o); o += EP;
    float* out2 = h1;   // reuse: h1 dead after layer-1 aggregation

    constexpr int SCAN_BLOCKS = (NN + 1023) / 1024;   // 98

    // ---- CSR build (shared by both layers) ----
    hipMemsetAsync(deg, 0, (size_t)NN * sizeof(int), stream);
    hipMemsetAsync(pool, 0, 64 * sizeof(float), stream);
    count_deg_kernel<<<(EP + 255) / 256, 256, 0, stream>>>(ei, deg);
    scan1_kernel<<<SCAN_BLOCKS, 256, 0, stream>>>(deg, row_ptr, partials);
    scan2_kernel<<<1, 64, 0, stream>>>(partials, SCAN_BLOCKS);
    scan3_kernel<<<(NN + 255) / 256, 256, 0, stream>>>(row_ptr, cursor, partials);
    scatter_kernel<<<(EP + 255) / 256, 256, 0, stream>>>(ei, cursor, csr_src);

    // ---- layer 1 ----
    gemm_kernel<256, 128><<<(NN + 7) / 8, 256, 0, stream>>>(x, W1, h1);
    alpha_kernel<2, 64><<<(NN * 2 + 255) / 256, 256, 0, stream>>>(h1, a_src1, a_dst1, as1, ad1);
    agg1_kernel<<<(NN + 3) / 4, 256, 0, stream>>>(row_ptr, csr_src, h1, as1, ad1, b1, out1);

    // ---- layer 2 ----
    gemm_kernel<128, 64><<<(NN + 15) / 16, 256, 0, stream>>>(out1, W2, h2);
    alpha_kernel<1, 64><<<(NN + 255) / 256, 256, 0, stream>>>(h2, a_src2, a_dst2, as2, ad2);
    agg2_kernel<<<(NN + 3) / 4, 256, 0, stream>>>(row_ptr, csr_src, h2, as2, ad2, b2, out2);

    // ---- MLP head + global mean pool ----
    mlp_pool_kernel<<<2048, 256, 0, stream>>>(out2, Wl1, bl1, Wl2, bl2, pool);
    finalize_kernel<<<1, 64, 0, stream>>>(pool, out);
}

// Round 12
// 947.845 us; speedup vs baseline: 5.6885x; 1.4626x over previous
//
#include <hip/hip_runtime.h>
#include <hip/hip_bf16.h>

constexpr int NN = 100000;            // nodes
constexpr int NE = 1600000;           // edges (without self loops)
constexpr int EP = NE + NN;           // edges incl. self loops
constexpr float NEG = 0.2f;           // leaky relu slope

__device__ __forceinline__ float elu_f(float x) { return x > 0.f ? x : __expf(x) - 1.f; }

__device__ __forceinline__ void f4fma(float4& a, float s, const float4& b) {
    a.x += s * b.x; a.y += s * b.y; a.z += s * b.z; a.w += s * b.w;
}

// ---------------- LDS-tiled GEMM: H[N,M] = X[N,K] @ W[K,M] ----------------
// Block: 256 threads -> output tile [BN nodes x M cols]; per-thread 8x8 register tile.
// K staged in KT=32 tiles: Xs transposed [k][node] (b128 compute reads), Ws flat.
template<int K, int M, int BN>
__global__ __launch_bounds__(256) void gemm_tiled(const float* __restrict__ X,
                                                  const float* __restrict__ W,
                                                  float* __restrict__ H) {
    constexpr int KT = 32;
    constexpr int CG = M / 8;           // col groups of 8
    constexpr int NG = 256 / CG;        // node groups of 8
    static_assert(NG * 8 == BN, "BN must equal 8*256/CG");
    __shared__ float Xs[KT * BN];
    __shared__ float Ws[KT * M];
    int tid = threadIdx.x;
    int cg = tid % CG, ng = tid / CG;
    int n0 = ng * 8, c0 = cg * 8;
    int nodeBase = blockIdx.x * BN;

    float4 acc[8][2];
#pragma unroll
    for (int i = 0; i < 8; ++i) {
        acc[i][0] = make_float4(0.f, 0.f, 0.f, 0.f);
        acc[i][1] = make_float4(0.f, 0.f, 0.f, 0.f);
    }

    for (int k0 = 0; k0 < K; k0 += KT) {
        // ---- stage X tile, transposed: Xs[k][node] ----
#pragma unroll
        for (int r = 0; r < BN / 32; ++r) {      // 8 threads per row, 32 rows per pass
            int ln = tid / 8 + 32 * r;
            int kk = (tid % 8) * 4;
            int node = nodeBase + ln;
            node = node < NN ? node : NN - 1;    // clamp; OOB accs discarded at store
            float4 v = *reinterpret_cast<const float4*>(X + (size_t)node * K + k0 + kk);
            Xs[(kk + 0) * BN + ln] = v.x;
            Xs[(kk + 1) * BN + ln] = v.y;
            Xs[(kk + 2) * BN + ln] = v.z;
            Xs[(kk + 3) * BN + ln] = v.w;
        }
        // ---- stage W tile, flat copy (rows k0..k0+KT are contiguous) ----
#pragma unroll
        for (int r = 0; r < (KT * M) / 1024; ++r) {
            int f = tid + 256 * r;
            *reinterpret_cast<float4*>(Ws + 4 * f) =
                *reinterpret_cast<const float4*>(W + (size_t)k0 * M + 4 * f);
        }
        __syncthreads();
        // ---- compute ----
#pragma unroll
        for (int k = 0; k < KT; ++k) {
            const float4 xa = *reinterpret_cast<const float4*>(Xs + k * BN + n0);
            const float4 xb = *reinterpret_cast<const float4*>(Xs + k * BN + n0 + 4);
            const float4 wa = *reinterpret_cast<const float4*>(Ws + k * M + c0);
            const float4 wb = *reinterpret_cast<const float4*>(Ws + k * M + c0 + 4);
            f4fma(acc[0][0], xa.x, wa); f4fma(acc[0][1], xa.x, wb);
            f4fma(acc[1][0], xa.y, wa); f4fma(acc[1][1], xa.y, wb);
            f4fma(acc[2][0], xa.z, wa); f4fma(acc[2][1], xa.z, wb);
            f4fma(acc[3][0], xa.w, wa); f4fma(acc[3][1], xa.w, wb);
            f4fma(acc[4][0], xb.x, wa); f4fma(acc[4][1], xb.x, wb);
            f4fma(acc[5][0], xb.y, wa); f4fma(acc[5][1], xb.y, wb);
            f4fma(acc[6][0], xb.z, wa); f4fma(acc[6][1], xb.z, wb);
            f4fma(acc[7][0], xb.w, wa); f4fma(acc[7][1], xb.w, wb);
        }
        __syncthreads();
    }
    // ---- store ----
#pragma unroll
    for (int i = 0; i < 8; ++i) {
        int node = nodeBase + n0 + i;
        if (node < NN) {
            *reinterpret_cast<float4*>(H + (size_t)node * M + c0)     = acc[i][0];
            *reinterpret_cast<float4*>(H + (size_t)node * M + c0 + 4) = acc[i][1];
        }
    }
}

// ---------------- per-node attention coefficients ----------------
template<int H, int C>
__global__ void alpha_kernel(const float* __restrict__ Hm, const float* __restrict__ a_src,
                             const float* __restrict__ a_dst,
                             float* __restrict__ as, float* __restrict__ ad) {
    int idx = blockIdx.x * blockDim.x + threadIdx.x;   // node*H + h
    if (idx >= NN * H) return;
    int node = idx / H, h = idx % H;
    const float* hr = Hm + (size_t)node * (H * C) + h * C;
    const float* sr = a_src + h * C;
    const float* dr = a_dst + h * C;
    float s = 0.f, d = 0.f;
#pragma unroll
    for (int c = 0; c < C; c += 4) {
        float4 hv = *reinterpret_cast<const float4*>(hr + c);
        float4 sv = *reinterpret_cast<const float4*>(sr + c);
        float4 dv = *reinterpret_cast<const float4*>(dr + c);
        s += hv.x * sv.x + hv.y * sv.y + hv.z * sv.z + hv.w * sv.w;
        d += hv.x * dv.x + hv.y * dv.y + hv.z * dv.z + hv.w * dv.w;
    }
    as[idx] = s; ad[idx] = d;
}

// ================= CSR build (by destination) =================
__global__ void count_deg_kernel(const int* __restrict__ ei, int* __restrict__ deg) {
    int i = blockIdx.x * blockDim.x + threadIdx.x;
    if (i >= EP) return;
    int d = (i < NE) ? ei[NE + i] : (i - NE);
    atomicAdd(&deg[d], 1);
}

// block-hierarchical exclusive scan over deg[NN] -> row_ptr (partial, pre-offset)
__global__ __launch_bounds__(256) void scan1_kernel(const int* __restrict__ deg,
                                                    int* __restrict__ excl,
                                                    int* __restrict__ partials) {
    __shared__ int ts[256];
    int tid = threadIdx.x;
    int idx0 = blockIdx.x * 1024 + tid * 4;
    int v0 = (idx0 + 0 < NN) ? deg[idx0 + 0] : 0;
    int v1 = (idx0 + 1 < NN) ? deg[idx0 + 1] : 0;
    int v2 = (idx0 + 2 < NN) ? deg[idx0 + 2] : 0;
    int v3 = (idx0 + 3 < NN) ? deg[idx0 + 3] : 0;
    int s0 = v0, s1 = s0 + v1, s2 = s1 + v2, s3 = s2 + v3;
    ts[tid] = s3;
    __syncthreads();
    for (int off = 1; off < 256; off <<= 1) {
        int t = (tid >= off) ? ts[tid - off] : 0;
        __syncthreads();
        ts[tid] += t;
        __syncthreads();
    }
    int te = ts[tid] - s3;   // exclusive offset of this thread within block
    if (idx0 + 0 < NN) excl[idx0 + 0] = te;
    if (idx0 + 1 < NN) excl[idx0 + 1] = te + s0;
    if (idx0 + 2 < NN) excl[idx0 + 2] = te + s1;
    if (idx0 + 3 < NN) excl[idx0 + 3] = te + s2;
    if (tid == 255) partials[blockIdx.x] = ts[255];
}

__global__ void scan2_kernel(int* __restrict__ partials, int nb) {
    if (threadIdx.x == 0 && blockIdx.x == 0) {
        int run = 0;
        for (int i = 0; i < nb; ++i) { int t = partials[i]; partials[i] = run; run += t; }
    }
}

__global__ void scan3_kernel(int* __restrict__ row_ptr, int* __restrict__ cursor,
                             const int* __restrict__ partials) {
    int i = blockIdx.x * blockDim.x + threadIdx.x;
    if (i == 0) row_ptr[NN] = EP;
    if (i >= NN) return;
    int v = row_ptr[i] + partials[i >> 10];
    row_ptr[i] = v;
    cursor[i] = v;
}

__global__ void scatter_kernel(const int* __restrict__ ei, int* __restrict__ cursor,
                               int* __restrict__ csr_src) {
    int i = blockIdx.x * blockDim.x + threadIdx.x;
    if (i >= EP) return;
    int s, d;
    if (i < NE) { s = ei[i]; d = ei[NE + i]; }
    else        { s = d = i - NE; }
    int pos = atomicAdd(&cursor[d], 1);
    csr_src[pos] = s;
}

// ================= gather aggregation (no atomics) =================
// Layer 1: H=2, C=64. One wave per node; lane handles channels 2*lane, 2*lane+1.
__global__ __launch_bounds__(256) void agg1_kernel(const int* __restrict__ rp,
                                                   const int* __restrict__ cs,
                                                   const float* __restrict__ h1,
                                                   const float* __restrict__ as,
                                                   const float* __restrict__ ad,
                                                   const float* __restrict__ b,
                                                   float* __restrict__ out1) {
    int wid = threadIdx.x >> 6, lane = threadIdx.x & 63;
    int node = blockIdx.x * 4 + wid;
    if (node >= NN) return;
    int h = lane >> 5;           // head for channels 2*lane, 2*lane+1
    int c0 = 2 * lane;
    float adv = ad[2 * node + h];
    float accx = 0.f, accy = 0.f, wsum = 0.f;
    int beg = rp[node], end = rp[node + 1];
    for (int j = beg; j < end; ++j) {
        int s = cs[j];
        float2 asv = *reinterpret_cast<const float2*>(as + 2 * s);
        float e = (h ? asv.y : asv.x) + adv;
        e = e > 0.f ? e : NEG * e;
        float w = __expf(e);
        float2 hv = *reinterpret_cast<const float2*>(h1 + (size_t)s * 128 + c0);
        accx += w * hv.x; accy += w * hv.y; wsum += w;
    }
    float inv = 1.f / (wsum + 1e-16f);
    float2 o;
    o.x = elu_f(accx * inv + b[c0 + 0]);
    o.y = elu_f(accy * inv + b[c0 + 1]);
    *reinterpret_cast<float2*>(out1 + (size_t)node * 128 + c0) = o;
}

// Layer 2: H=1, C=64. One wave per node; lane handles channel `lane`. +b2 fused.
__global__ __launch_bounds__(256) void agg2_kernel(const int* __restrict__ rp,
                                                   const int* __restrict__ cs,
                                                   const float* __restrict__ h2,
                                                   const float* __restrict__ as,
                                                   const float* __restrict__ ad,
                                                   const float* __restrict__ b2,
                                                   float* __restrict__ out2) {
    int wid = threadIdx.x >> 6, lane = threadIdx.x & 63;
    int node = blockIdx.x * 4 + wid;
    if (node >= NN) return;
    float adv = ad[node];
    float acc = 0.f, wsum = 0.f;
    int beg = rp[node], end = rp[node + 1];
    for (int j = beg; j < end; ++j) {
        int s = cs[j];
        float e = as[s] + adv;
        e = e > 0.f ? e : NEG * e;
        float w = __expf(e);
        acc += w * h2[(size_t)s * 64 + lane];
        wsum += w;
    }
    out2[(size_t)node * 64 + lane] = acc / (wsum + 1e-16f) + b2[lane];
}

// ---------------- MLP head + mean pool (b2 already fused into out2) ----------------
__global__ __launch_bounds__(256) void mlp_pool_kernel(const float* __restrict__ out2,
                                                       const float* __restrict__ Wl1,
                                                       const float* __restrict__ bl1,
                                                       const float* __restrict__ Wl2,
                                                       const float* __restrict__ bl2,
                                                       float* __restrict__ pool) {
    __shared__ float sW1[64 * 64];
    __shared__ float sW2[64 * 64];
    __shared__ float sv[4][64];
    __shared__ float st[4][64];
    __shared__ float sacc[256];
    int tid = threadIdx.x;
    for (int i = tid; i < 64 * 64; i += 256) { sW1[i] = Wl1[i]; sW2[i] = Wl2[i]; }
    __syncthreads();
    int ln = tid / 64, c = tid % 64;
    float bl1c = bl1[c], bl2c = bl2[c];
    float acc = 0.f;
    for (int base = blockIdx.x * 4; base < NN; base += gridDim.x * 4) {
        int node = base + ln;
        float v = 0.f;
        if (node < NN) v = out2[(size_t)node * 64 + c];
        sv[ln][c] = v;
        __syncthreads();
        float t = bl1c;
#pragma unroll
        for (int k = 0; k < 64; ++k) t += sv[ln][k] * sW1[k * 64 + c];
        t = t > 0.f ? t : __expf(t) - 1.f;
        st[ln][c] = t;
        __syncthreads();
        float o = bl2c;
#pragma unroll
        for (int k = 0; k < 64; ++k) o += st[ln][k] * sW2[k * 64 + c];
        if (node < NN) acc += o;
        __syncthreads();
    }
    sacc[tid] = acc;
    __syncthreads();
    if (tid < 64) {
        float r = sacc[tid] + sacc[64 + tid] + sacc[128 + tid] + sacc[192 + tid];
        atomicAdd(&pool[tid], r);
    }
}

__global__ void finalize_kernel(const float* __restrict__ pool, float* __restrict__ out) {
    int c = threadIdx.x;
    if (c < 64) out[c] = pool[c] * (1.0f / NN);
}

extern "C" void kernel_launch(void* const* d_in, const int* in_sizes, int n_in,
                              void* d_out, int out_size, void* d_ws, size_t ws_size,
                              hipStream_t stream) {
    const float* x      = (const float*)d_in[0];
    const int*   ei     = (const int*)d_in[1];
    const float* W1     = (const float*)d_in[2];
    const float* a_src1 = (const float*)d_in[3];
    const float* a_dst1 = (const float*)d_in[4];
    const float* b1     = (const float*)d_in[5];
    const float* W2     = (const float*)d_in[6];
    const float* a_src2 = (const float*)d_in[7];
    const float* a_dst2 = (const float*)d_in[8];
    const float* b2     = (const float*)d_in[9];
    const float* Wl1    = (const float*)d_in[10];
    const float* bl1    = (const float*)d_in[11];
    const float* Wl2    = (const float*)d_in[12];
    const float* bl2    = (const float*)d_in[13];
    float* out = (float*)d_out;

    float* ws = (float*)d_ws;
    size_t o = 0;
    float* h1      = ws + o; o += (size_t)NN * 128;   // [N,2,64]
    float* out1    = ws + o; o += (size_t)NN * 128;
    float* h2      = ws + o; o += (size_t)NN * 64;
    float* as1     = ws + o; o += NN * 2;
    float* ad1     = ws + o; o += NN * 2;
    float* as2     = ws + o; o += NN;
    float* ad2     = ws + o; o += NN;
    float* pool    = ws + o; o += 64;
    int* deg       = (int*)(ws + o); o += NN;
    int* row_ptr   = (int*)(ws + o); o += NN + 2;
    int* cursor    = (int*)(ws + o); o += NN;
    int* partials  = (int*)(ws + o); o += 128;
    int* csr_src   = (int*)(ws + o); o += EP;
    float* out2 = h1;   // reuse: h1 dead after layer-1 aggregation

    constexpr int SCAN_BLOCKS = (NN + 1023) / 1024;   // 98

    // ---- CSR build (shared by both layers) ----
    hipMemsetAsync(deg, 0, (size_t)NN * sizeof(int), stream);
    hipMemsetAsync(pool, 0, 64 * sizeof(float), stream);
    count_deg_kernel<<<(EP + 255) / 256, 256, 0, stream>>>(ei, deg);
    scan1_kernel<<<SCAN_BLOCKS, 256, 0, stream>>>(deg, row_ptr, partials);
    scan2_kernel<<<1, 64, 0, stream>>>(partials, SCAN_BLOCKS);
    scan3_kernel<<<(NN + 255) / 256, 256, 0, stream>>>(row_ptr, cursor, partials);
    scatter_kernel<<<(EP + 255) / 256, 256, 0, stream>>>(ei, cursor, csr_src);

    // ---- layer 1 ----
    gemm_tiled<256, 128, 128><<<(NN + 127) / 128, 256, 0, stream>>>(x, W1, h1);
    alpha_kernel<2, 64><<<(NN * 2 + 255) / 256, 256, 0, stream>>>(h1, a_src1, a_dst1, as1, ad1);
    agg1_kernel<<<(NN + 3) / 4, 256, 0, stream>>>(row_ptr, csr_src, h1, as1, ad1, b1, out1);

    // ---- layer 2 ----
    gemm_tiled<128, 64, 256><<<(NN + 255) / 256, 256, 0, stream>>>(out1, W2, h2);
    alpha_kernel<1, 64><<<(NN + 255) / 256, 256, 0, stream>>>(h2, a_src2, a_dst2, as2, ad2);
    agg2_kernel<<<(NN + 3) / 4, 256, 0, stream>>>(row_ptr, csr_src, h2, as2, ad2, b2, out2);

    // ---- MLP head + global mean pool ----
    mlp_pool_kernel<<<2048, 256, 0, stream>>>(out2, Wl1, bl1, Wl2, bl2, pool);
    finalize_kernel<<<1, 64, 0, stream>>>(pool, out);
}

// Round 13
// 832.999 us; speedup vs baseline: 6.4728x; 1.1379x over previous
//
#include <hip/hip_runtime.h>
#include <hip/hip_bf16.h>

constexpr int NN = 100000;            // nodes
constexpr int NE = 1600000;           // edges (without self loops)
constexpr int EP = NE + NN;           // edges incl. self loops
constexpr float NEG = 0.2f;           // leaky relu slope

__device__ __forceinline__ float elu_f(float x) { return x > 0.f ? x : __expf(x) - 1.f; }

__device__ __forceinline__ void f4fma(float4& a, float s, const float4& b) {
    a.x += s * b.x; a.y += s * b.y; a.z += s * b.z; a.w += s * b.w;
}

// ---------------- LDS-tiled GEMM: H[N,M] = X[N,K] @ W[K,M] ----------------
template<int K, int M, int BN>
__global__ __launch_bounds__(256) void gemm_tiled(const float* __restrict__ X,
                                                  const float* __restrict__ W,
                                                  float* __restrict__ H) {
    constexpr int KT = 32;
    constexpr int CG = M / 8;           // col groups of 8
    constexpr int NG = 256 / CG;        // node groups of 8
    static_assert(NG * 8 == BN, "BN must equal 8*256/CG");
    __shared__ float Xs[KT * BN];
    __shared__ float Ws[KT * M];
    int tid = threadIdx.x;
    int cg = tid % CG, ng = tid / CG;
    int n0 = ng * 8, c0 = cg * 8;
    int nodeBase = blockIdx.x * BN;

    float4 acc[8][2];
#pragma unroll
    for (int i = 0; i < 8; ++i) {
        acc[i][0] = make_float4(0.f, 0.f, 0.f, 0.f);
        acc[i][1] = make_float4(0.f, 0.f, 0.f, 0.f);
    }

    for (int k0 = 0; k0 < K; k0 += KT) {
#pragma unroll
        for (int r = 0; r < BN / 32; ++r) {
            int ln = tid / 8 + 32 * r;
            int kk = (tid % 8) * 4;
            int node = nodeBase + ln;
            node = node < NN ? node : NN - 1;
            float4 v = *reinterpret_cast<const float4*>(X + (size_t)node * K + k0 + kk);
            Xs[(kk + 0) * BN + ln] = v.x;
            Xs[(kk + 1) * BN + ln] = v.y;
            Xs[(kk + 2) * BN + ln] = v.z;
            Xs[(kk + 3) * BN + ln] = v.w;
        }
#pragma unroll
        for (int r = 0; r < (KT * M) / 1024; ++r) {
            int f = tid + 256 * r;
            *reinterpret_cast<float4*>(Ws + 4 * f) =
                *reinterpret_cast<const float4*>(W + (size_t)k0 * M + 4 * f);
        }
        __syncthreads();
#pragma unroll
        for (int k = 0; k < KT; ++k) {
            const float4 xa = *reinterpret_cast<const float4*>(Xs + k * BN + n0);
            const float4 xb = *reinterpret_cast<const float4*>(Xs + k * BN + n0 + 4);
            const float4 wa = *reinterpret_cast<const float4*>(Ws + k * M + c0);
            const float4 wb = *reinterpret_cast<const float4*>(Ws + k * M + c0 + 4);
            f4fma(acc[0][0], xa.x, wa); f4fma(acc[0][1], xa.x, wb);
            f4fma(acc[1][0], xa.y, wa); f4fma(acc[1][1], xa.y, wb);
            f4fma(acc[2][0], xa.z, wa); f4fma(acc[2][1], xa.z, wb);
            f4fma(acc[3][0], xa.w, wa); f4fma(acc[3][1], xa.w, wb);
            f4fma(acc[4][0], xb.x, wa); f4fma(acc[4][1], xb.x, wb);
            f4fma(acc[5][0], xb.y, wa); f4fma(acc[5][1], xb.y, wb);
            f4fma(acc[6][0], xb.z, wa); f4fma(acc[6][1], xb.z, wb);
            f4fma(acc[7][0], xb.w, wa); f4fma(acc[7][1], xb.w, wb);
        }
        __syncthreads();
    }
#pragma unroll
    for (int i = 0; i < 8; ++i) {
        int node = nodeBase + n0 + i;
        if (node < NN) {
            *reinterpret_cast<float4*>(H + (size_t)node * M + c0)     = acc[i][0];
            *reinterpret_cast<float4*>(H + (size_t)node * M + c0 + 4) = acc[i][1];
        }
    }
}

// ---------------- per-node attention coefficients ----------------
template<int H, int C>
__global__ void alpha_kernel(const float* __restrict__ Hm, const float* __restrict__ a_src,
                             const float* __restrict__ a_dst,
                             float* __restrict__ as, float* __restrict__ ad) {
    int idx = blockIdx.x * blockDim.x + threadIdx.x;   // node*H + h
    if (idx >= NN * H) return;
    int node = idx / H, h = idx % H;
    const float* hr = Hm + (size_t)node * (H * C) + h * C;
    const float* sr = a_src + h * C;
    const float* dr = a_dst + h * C;
    float s = 0.f, d = 0.f;
#pragma unroll
    for (int c = 0; c < C; c += 4) {
        float4 hv = *reinterpret_cast<const float4*>(hr + c);
        float4 sv = *reinterpret_cast<const float4*>(sr + c);
        float4 dv = *reinterpret_cast<const float4*>(dr + c);
        s += hv.x * sv.x + hv.y * sv.y + hv.z * sv.z + hv.w * sv.w;
        d += hv.x * dv.x + hv.y * dv.y + hv.z * dv.z + hv.w * dv.w;
    }
    as[idx] = s; ad[idx] = d;
}

// ================= CSR build (by destination) =================
__global__ void count_deg_kernel(const int* __restrict__ ei, int* __restrict__ deg) {
    int i = blockIdx.x * blockDim.x + threadIdx.x;
    if (i >= EP) return;
    int d = (i < NE) ? ei[NE + i] : (i - NE);
    atomicAdd(&deg[d], 1);
}

__global__ __launch_bounds__(256) void scan1_kernel(const int* __restrict__ deg,
                                                    int* __restrict__ excl,
                                                    int* __restrict__ partials) {
    __shared__ int ts[256];
    int tid = threadIdx.x;
    int idx0 = blockIdx.x * 1024 + tid * 4;
    int v0 = (idx0 + 0 < NN) ? deg[idx0 + 0] : 0;
    int v1 = (idx0 + 1 < NN) ? deg[idx0 + 1] : 0;
    int v2 = (idx0 + 2 < NN) ? deg[idx0 + 2] : 0;
    int v3 = (idx0 + 3 < NN) ? deg[idx0 + 3] : 0;
    int s0 = v0, s1 = s0 + v1, s2 = s1 + v2, s3 = s2 + v3;
    ts[tid] = s3;
    __syncthreads();
    for (int off = 1; off < 256; off <<= 1) {
        int t = (tid >= off) ? ts[tid - off] : 0;
        __syncthreads();
        ts[tid] += t;
        __syncthreads();
    }
    int te = ts[tid] - s3;
    if (idx0 + 0 < NN) excl[idx0 + 0] = te;
    if (idx0 + 1 < NN) excl[idx0 + 1] = te + s0;
    if (idx0 + 2 < NN) excl[idx0 + 2] = te + s1;
    if (idx0 + 3 < NN) excl[idx0 + 3] = te + s2;
    if (tid == 255) partials[blockIdx.x] = ts[255];
}

__global__ void scan2_kernel(int* __restrict__ partials, int nb) {
    if (threadIdx.x == 0 && blockIdx.x == 0) {
        int run = 0;
        for (int i = 0; i < nb; ++i) { int t = partials[i]; partials[i] = run; run += t; }
    }
}

__global__ void scan3_kernel(int* __restrict__ row_ptr, int* __restrict__ cursor,
                             const int* __restrict__ partials) {
    int i = blockIdx.x * blockDim.x + threadIdx.x;
    if (i == 0) row_ptr[NN] = EP;
    if (i >= NN) return;
    int v = row_ptr[i] + partials[i >> 10];
    row_ptr[i] = v;
    cursor[i] = v;
}

__global__ void scatter_kernel(const int* __restrict__ ei, int* __restrict__ cursor,
                               int* __restrict__ csr_src) {
    int i = blockIdx.x * blockDim.x + threadIdx.x;
    if (i >= EP) return;
    int s, d;
    if (i < NE) { s = ei[i]; d = ei[NE + i]; }
    else        { s = d = i - NE; }
    int pos = atomicAdd(&cursor[d], 1);
    csr_src[pos] = s;
}

// ================= gather aggregation (no atomics, software-pipelined) =================
// Layer 1: H=2, C=64. One wave per node; lane handles channels 2*lane, 2*lane+1.
// Pipeline: index prefetch 2 ahead, data prefetch 1 ahead (deg>=1 via self-loop).
__global__ __launch_bounds__(256) void agg1_kernel(const int* __restrict__ rp,
                                                   const int* __restrict__ cs,
                                                   const float* __restrict__ h1,
                                                   const float* __restrict__ as,
                                                   const float* __restrict__ ad,
                                                   const float* __restrict__ b,
                                                   float* __restrict__ out1) {
    int wid = threadIdx.x >> 6, lane = threadIdx.x & 63;
    int node = blockIdx.x * 4 + wid;
    if (node >= NN) return;
    int h = lane >> 5;
    int c0 = 2 * lane;
    float adv = ad[2 * node + h];
    float accx = 0.f, accy = 0.f, wsum = 0.f;
    int beg = rp[node], end = rp[node + 1];

    int sA = cs[beg];                                  // deg >= 1 always (self-loop)
    int sB = (beg + 1 < end) ? cs[beg + 1] : 0;
    float2 asA = *reinterpret_cast<const float2*>(as + 2 * sA);
    float2 hvA = *reinterpret_cast<const float2*>(h1 + (size_t)sA * 128 + c0);
    for (int j = beg; j < end; ++j) {
        int sC = (j + 2 < end) ? cs[j + 2] : 0;        // index for j+2
        float2 asB = *reinterpret_cast<const float2*>(as + 2 * sB);              // data j+1
        float2 hvB = *reinterpret_cast<const float2*>(h1 + (size_t)sB * 128 + c0);
        float e = (h ? asA.y : asA.x) + adv;           // compute j
        e = e > 0.f ? e : NEG * e;
        float w = __expf(e);
        accx += w * hvA.x; accy += w * hvA.y; wsum += w;
        asA = asB; hvA = hvB; sB = sC;                 // rotate
    }
    float inv = 1.f / (wsum + 1e-16f);
    float2 o;
    o.x = elu_f(accx * inv + b[c0 + 0]);
    o.y = elu_f(accy * inv + b[c0 + 1]);
    *reinterpret_cast<float2*>(out1 + (size_t)node * 128 + c0) = o;
}

// Layer 2: H=1, C=64. One wave per node; lane handles channel `lane`. +b2 fused.
__global__ __launch_bounds__(256) void agg2_kernel(const int* __restrict__ rp,
                                                   const int* __restrict__ cs,
                                                   const float* __restrict__ h2,
                                                   const float* __restrict__ as,
                                                   const float* __restrict__ ad,
                                                   const float* __restrict__ b2,
                                                   float* __restrict__ out2) {
    int wid = threadIdx.x >> 6, lane = threadIdx.x & 63;
    int node = blockIdx.x * 4 + wid;
    if (node >= NN) return;
    float adv = ad[node];
    float acc = 0.f, wsum = 0.f;
    int beg = rp[node], end = rp[node + 1];

    int sA = cs[beg];
    int sB = (beg + 1 < end) ? cs[beg + 1] : 0;
    float asA = as[sA];
    float hvA = h2[(size_t)sA * 64 + lane];
    for (int j = beg; j < end; ++j) {
        int sC = (j + 2 < end) ? cs[j + 2] : 0;
        float asB = as[sB];
        float hvB = h2[(size_t)sB * 64 + lane];
        float e = asA + adv;
        e = e > 0.f ? e : NEG * e;
        float w = __expf(e);
        acc += w * hvA; wsum += w;
        asA = asB; hvA = hvB; sB = sC;
    }
    out2[(size_t)node * 64 + lane] = acc / (wsum + 1e-16f) + b2[lane];
}

// ---------------- MLP head + mean pool (b2 already fused into out2) ----------------
__global__ __launch_bounds__(256) void mlp_pool_kernel(const float* __restrict__ out2,
                                                       const float* __restrict__ Wl1,
                                                       const float* __restrict__ bl1,
                                                       const float* __restrict__ Wl2,
                                                       const float* __restrict__ bl2,
                                                       float* __restrict__ pool) {
    __shared__ float sW1[64 * 64];
    __shared__ float sW2[64 * 64];
    __shared__ float sv[4][64];
    __shared__ float st[4][64];
    __shared__ float sacc[256];
    int tid = threadIdx.x;
    for (int i = tid; i < 64 * 64; i += 256) { sW1[i] = Wl1[i]; sW2[i] = Wl2[i]; }
    __syncthreads();
    int ln = tid / 64, c = tid % 64;
    float bl1c = bl1[c], bl2c = bl2[c];
    float acc = 0.f;
    for (int base = blockIdx.x * 4; base < NN; base += gridDim.x * 4) {
        int node = base + ln;
        float v = 0.f;
        if (node < NN) v = out2[(size_t)node * 64 + c];
        sv[ln][c] = v;
        __syncthreads();
        float t = bl1c;
#pragma unroll
        for (int k = 0; k < 64; ++k) t += sv[ln][k] * sW1[k * 64 + c];
        t = t > 0.f ? t : __expf(t) - 1.f;
        st[ln][c] = t;
        __syncthreads();
        float o = bl2c;
#pragma unroll
        for (int k = 0; k < 64; ++k) o += st[ln][k] * sW2[k * 64 + c];
        if (node < NN) acc += o;
        __syncthreads();
    }
    sacc[tid] = acc;
    __syncthreads();
    if (tid < 64) {
        float r = sacc[tid] + sacc[64 + tid] + sacc[128 + tid] + sacc[192 + tid];
        atomicAdd(&pool[tid], r);
    }
}

__global__ void finalize_kernel(const float* __restrict__ pool, float* __restrict__ out) {
    int c = threadIdx.x;
    if (c < 64) out[c] = pool[c] * (1.0f / NN);
}

extern "C" void kernel_launch(void* const* d_in, const int* in_sizes, int n_in,
                              void* d_out, int out_size, void* d_ws, size_t ws_size,
                              hipStream_t stream) {
    const float* x      = (const float*)d_in[0];
    const int*   ei     = (const int*)d_in[1];
    const float* W1     = (const float*)d_in[2];
    const float* a_src1 = (const float*)d_in[3];
    const float* a_dst1 = (const float*)d_in[4];
    const float* b1     = (const float*)d_in[5];
    const float* W2     = (const float*)d_in[6];
    const float* a_src2 = (const float*)d_in[7];
    const float* a_dst2 = (const float*)d_in[8];
    const float* b2     = (const float*)d_in[9];
    const float* Wl1    = (const float*)d_in[10];
    const float* bl1    = (const float*)d_in[11];
    const float* Wl2    = (const float*)d_in[12];
    const float* bl2    = (const float*)d_in[13];
    float* out = (float*)d_out;

    float* ws = (float*)d_ws;
    size_t o = 0;
    float* h1      = ws + o; o += (size_t)NN * 128;   // [N,2,64]
    float* out1    = ws + o; o += (size_t)NN * 128;
    float* h2      = ws + o; o += (size_t)NN * 64;
    float* as1     = ws + o; o += NN * 2;
    float* ad1     = ws + o; o += NN * 2;
    float* as2     = ws + o; o += NN;
    float* ad2     = ws + o; o += NN;
    float* pool    = ws + o; o += 64;
    int* deg       = (int*)(ws + o); o += NN;
    int* row_ptr   = (int*)(ws + o); o += NN + 2;
    int* cursor    = (int*)(ws + o); o += NN;
    int* partials  = (int*)(ws + o); o += 128;
    int* csr_src   = (int*)(ws + o); o += EP;
    float* out2 = h1;   // reuse: h1 dead after layer-1 aggregation

    constexpr int SCAN_BLOCKS = (NN + 1023) / 1024;   // 98

    // ---- CSR build (shared by both layers) ----
    hipMemsetAsync(deg, 0, (size_t)NN * sizeof(int), stream);
    hipMemsetAsync(pool, 0, 64 * sizeof(float), stream);
    count_deg_kernel<<<(EP + 255) / 256, 256, 0, stream>>>(ei, deg);
    scan1_kernel<<<SCAN_BLOCKS, 256, 0, stream>>>(deg, row_ptr, partials);
    scan2_kernel<<<1, 64, 0, stream>>>(partials, SCAN_BLOCKS);
    scan3_kernel<<<(NN + 255) / 256, 256, 0, stream>>>(row_ptr, cursor, partials);
    scatter_kernel<<<(EP + 255) / 256, 256, 0, stream>>>(ei, cursor, csr_src);

    // ---- layer 1 ----
    gemm_tiled<256, 128, 128><<<(NN + 127) / 128, 256, 0, stream>>>(x, W1, h1);
    alpha_kernel<2, 64><<<(NN * 2 + 255) / 256, 256, 0, stream>>>(h1, a_src1, a_dst1, as1, ad1);
    agg1_kernel<<<(NN + 3) / 4, 256, 0, stream>>>(row_ptr, csr_src, h1, as1, ad1, b1, out1);

    // ---- layer 2 ----
    gemm_tiled<128, 64, 256><<<(NN + 255) / 256, 256, 0, stream>>>(out1, W2, h2);
    alpha_kernel<1, 64><<<(NN + 255) / 256, 256, 0, stream>>>(h2, a_src2, a_dst2, as2, ad2);
    agg2_kernel<<<(NN + 3) / 4, 256, 0, stream>>>(row_ptr, csr_src, h2, as2, ad2, b2, out2);

    // ---- MLP head + global mean pool ----
    mlp_pool_kernel<<<2048, 256, 0, stream>>>(out2, Wl1, bl1, Wl2, bl2, pool);
    finalize_kernel<<<1, 64, 0, stream>>>(pool, out);
}

// Round 14
// 826.910 us; speedup vs baseline: 6.5205x; 1.0074x over previous
//
#include <hip/hip_runtime.h>
#include <hip/hip_bf16.h>

constexpr int NN = 100000;            // nodes
constexpr int NE = 1600000;           // edges (without self loops)
constexpr int EP = NE + NN;           // edges incl. self loops
constexpr float NEG = 0.2f;           // leaky relu slope

__device__ __forceinline__ float elu_f(float x) { return x > 0.f ? x : __expf(x) - 1.f; }

__device__ __forceinline__ void f4fma(float4& a, float s, const float4& b) {
    a.x += s * b.x; a.y += s * b.y; a.z += s * b.z; a.w += s * b.w;
}

// round-to-nearest-even f32 -> bf16 (values are finite; no NaN handling needed)
__device__ __forceinline__ unsigned short bf16rne(float f) {
    unsigned int u = __float_as_uint(f);
    u += 0x7fffu + ((u >> 16) & 1u);
    return (unsigned short)(u >> 16);
}
__device__ __forceinline__ unsigned int pk2(float lo, float hi) {
    return (unsigned int)bf16rne(lo) | ((unsigned int)bf16rne(hi) << 16);
}

// ---------------- LDS-tiled GEMM: H[N,M] = X[N,K] @ W[K,M]; also writes bf16 copy Hb ----------------
template<int K, int M, int BN>
__global__ __launch_bounds__(256) void gemm_tiled(const float* __restrict__ X,
                                                  const float* __restrict__ W,
                                                  float* __restrict__ H,
                                                  unsigned short* __restrict__ Hb) {
    constexpr int KT = 32;
    constexpr int CG = M / 8;           // col groups of 8
    constexpr int NG = 256 / CG;        // node groups of 8
    static_assert(NG * 8 == BN, "BN must equal 8*256/CG");
    __shared__ float Xs[KT * BN];
    __shared__ float Ws[KT * M];
    int tid = threadIdx.x;
    int cg = tid % CG, ng = tid / CG;
    int n0 = ng * 8, c0 = cg * 8;
    int nodeBase = blockIdx.x * BN;

    float4 acc[8][2];
#pragma unroll
    for (int i = 0; i < 8; ++i) {
        acc[i][0] = make_float4(0.f, 0.f, 0.f, 0.f);
        acc[i][1] = make_float4(0.f, 0.f, 0.f, 0.f);
    }

    for (int k0 = 0; k0 < K; k0 += KT) {
#pragma unroll
        for (int r = 0; r < BN / 32; ++r) {
            int ln = tid / 8 + 32 * r;
            int kk = (tid % 8) * 4;
            int node = nodeBase + ln;
            node = node < NN ? node : NN - 1;
            float4 v = *reinterpret_cast<const float4*>(X + (size_t)node * K + k0 + kk);
            Xs[(kk + 0) * BN + ln] = v.x;
            Xs[(kk + 1) * BN + ln] = v.y;
            Xs[(kk + 2) * BN + ln] = v.z;
            Xs[(kk + 3) * BN + ln] = v.w;
        }
#pragma unroll
        for (int r = 0; r < (KT * M) / 1024; ++r) {
            int f = tid + 256 * r;
            *reinterpret_cast<float4*>(Ws + 4 * f) =
                *reinterpret_cast<const float4*>(W + (size_t)k0 * M + 4 * f);
        }
        __syncthreads();
#pragma unroll
        for (int k = 0; k < KT; ++k) {
            const float4 xa = *reinterpret_cast<const float4*>(Xs + k * BN + n0);
            const float4 xb = *reinterpret_cast<const float4*>(Xs + k * BN + n0 + 4);
            const float4 wa = *reinterpret_cast<const float4*>(Ws + k * M + c0);
            const float4 wb = *reinterpret_cast<const float4*>(Ws + k * M + c0 + 4);
            f4fma(acc[0][0], xa.x, wa); f4fma(acc[0][1], xa.x, wb);
            f4fma(acc[1][0], xa.y, wa); f4fma(acc[1][1], xa.y, wb);
            f4fma(acc[2][0], xa.z, wa); f4fma(acc[2][1], xa.z, wb);
            f4fma(acc[3][0], xa.w, wa); f4fma(acc[3][1], xa.w, wb);
            f4fma(acc[4][0], xb.x, wa); f4fma(acc[4][1], xb.x, wb);
            f4fma(acc[5][0], xb.y, wa); f4fma(acc[5][1], xb.y, wb);
            f4fma(acc[6][0], xb.z, wa); f4fma(acc[6][1], xb.z, wb);
            f4fma(acc[7][0], xb.w, wa); f4fma(acc[7][1], xb.w, wb);
        }
        __syncthreads();
    }
#pragma unroll
    for (int i = 0; i < 8; ++i) {
        int node = nodeBase + n0 + i;
        if (node < NN) {
            *reinterpret_cast<float4*>(H + (size_t)node * M + c0)     = acc[i][0];
            *reinterpret_cast<float4*>(H + (size_t)node * M + c0 + 4) = acc[i][1];
            uint4 p;
            p.x = pk2(acc[i][0].x, acc[i][0].y);
            p.y = pk2(acc[i][0].z, acc[i][0].w);
            p.z = pk2(acc[i][1].x, acc[i][1].y);
            p.w = pk2(acc[i][1].z, acc[i][1].w);
            *reinterpret_cast<uint4*>(Hb + (size_t)node * M + c0) = p;
        }
    }
}

// ---------------- per-node attention coefficients ----------------
template<int H, int C>
__global__ void alpha_kernel(const float* __restrict__ Hm, const float* __restrict__ a_src,
                             const float* __restrict__ a_dst,
                             float* __restrict__ as, float* __restrict__ ad) {
    int idx = blockIdx.x * blockDim.x + threadIdx.x;   // node*H + h
    if (idx >= NN * H) return;
    int node = idx / H, h = idx % H;
    const float* hr = Hm + (size_t)node * (H * C) + h * C;
    const float* sr = a_src + h * C;
    const float* dr = a_dst + h * C;
    float s = 0.f, d = 0.f;
#pragma unroll
    for (int c = 0; c < C; c += 4) {
        float4 hv = *reinterpret_cast<const float4*>(hr + c);
        float4 sv = *reinterpret_cast<const float4*>(sr + c);
        float4 dv = *reinterpret_cast<const float4*>(dr + c);
        s += hv.x * sv.x + hv.y * sv.y + hv.z * sv.z + hv.w * sv.w;
        d += hv.x * dv.x + hv.y * dv.y + hv.z * dv.z + hv.w * dv.w;
    }
    as[idx] = s; ad[idx] = d;
}

// ================= CSR build (by destination) =================
__global__ void count_deg_kernel(const int* __restrict__ ei, int* __restrict__ deg) {
    int i = blockIdx.x * blockDim.x + threadIdx.x;
    if (i >= EP) return;
    int d = (i < NE) ? ei[NE + i] : (i - NE);
    atomicAdd(&deg[d], 1);
}

__global__ __launch_bounds__(256) void scan1_kernel(const int* __restrict__ deg,
                                                    int* __restrict__ excl,
                                                    int* __restrict__ partials) {
    __shared__ int ts[256];
    int tid = threadIdx.x;
    int idx0 = blockIdx.x * 1024 + tid * 4;
    int v0 = (idx0 + 0 < NN) ? deg[idx0 + 0] : 0;
    int v1 = (idx0 + 1 < NN) ? deg[idx0 + 1] : 0;
    int v2 = (idx0 + 2 < NN) ? deg[idx0 + 2] : 0;
    int v3 = (idx0 + 3 < NN) ? deg[idx0 + 3] : 0;
    int s0 = v0, s1 = s0 + v1, s2 = s1 + v2, s3 = s2 + v3;
    ts[tid] = s3;
    __syncthreads();
    for (int off = 1; off < 256; off <<= 1) {
        int t = (tid >= off) ? ts[tid - off] : 0;
        __syncthreads();
        ts[tid] += t;
        __syncthreads();
    }
    int te = ts[tid] - s3;
    if (idx0 + 0 < NN) excl[idx0 + 0] = te;
    if (idx0 + 1 < NN) excl[idx0 + 1] = te + s0;
    if (idx0 + 2 < NN) excl[idx0 + 2] = te + s1;
    if (idx0 + 3 < NN) excl[idx0 + 3] = te + s2;
    if (tid == 255) partials[blockIdx.x] = ts[255];
}

__global__ void scan2_kernel(int* __restrict__ partials, int nb) {
    if (threadIdx.x == 0 && blockIdx.x == 0) {
        int run = 0;
        for (int i = 0; i < nb; ++i) { int t = partials[i]; partials[i] = run; run += t; }
    }
}

__global__ void scan3_kernel(int* __restrict__ row_ptr, int* __restrict__ cursor,
                             const int* __restrict__ partials) {
    int i = blockIdx.x * blockDim.x + threadIdx.x;
    if (i == 0) row_ptr[NN] = EP;
    if (i >= NN) return;
    int v = row_ptr[i] + partials[i >> 10];
    row_ptr[i] = v;
    cursor[i] = v;
}

__global__ void scatter_kernel(const int* __restrict__ ei, int* __restrict__ cursor,
                               int* __restrict__ csr_src) {
    int i = blockIdx.x * blockDim.x + threadIdx.x;
    if (i >= EP) return;
    int s, d;
    if (i < NE) { s = ei[i]; d = ei[NE + i]; }
    else        { s = d = i - NE; }
    int pos = atomicAdd(&cursor[d], 1);
    csr_src[pos] = s;
}

// ================= gather aggregation (no atomics, software-pipelined, bf16 gather) =================
// Layer 1: H=2, C=64. One wave per node; lane handles channels 2*lane, 2*lane+1 (bf16-packed dword).
__global__ __launch_bounds__(256) void agg1_kernel(const int* __restrict__ rp,
                                                   const int* __restrict__ cs,
                                                   const unsigned short* __restrict__ h1b,
                                                   const float* __restrict__ as,
                                                   const float* __restrict__ ad,
                                                   const float* __restrict__ b,
                                                   float* __restrict__ out1) {
    int wid = threadIdx.x >> 6, lane = threadIdx.x & 63;
    int node = blockIdx.x * 4 + wid;
    if (node >= NN) return;
    int h = lane >> 5;
    int c0 = 2 * lane;
    float adv = ad[2 * node + h];
    float accx = 0.f, accy = 0.f, wsum = 0.f;
    int beg = rp[node], end = rp[node + 1];

    int sA = cs[beg];                                  // deg >= 1 always (self-loop)
    int sB = (beg + 1 < end) ? cs[beg + 1] : 0;
    float2 asA = *reinterpret_cast<const float2*>(as + 2 * sA);
    unsigned int pA = *reinterpret_cast<const unsigned int*>(h1b + (size_t)sA * 128 + c0);
    for (int j = beg; j < end; ++j) {
        int sC = (j + 2 < end) ? cs[j + 2] : 0;        // index for j+2
        float2 asB = *reinterpret_cast<const float2*>(as + 2 * sB);            // data j+1
        unsigned int pB = *reinterpret_cast<const unsigned int*>(h1b + (size_t)sB * 128 + c0);
        float e = (h ? asA.y : asA.x) + adv;           // compute j
        e = e > 0.f ? e : NEG * e;
        float w = __expf(e);
        float hx = __uint_as_float(pA << 16);          // channel c0
        float hy = __uint_as_float(pA & 0xffff0000u);  // channel c0+1
        accx += w * hx; accy += w * hy; wsum += w;
        asA = asB; pA = pB; sB = sC;                   // rotate
    }
    float inv = 1.f / (wsum + 1e-16f);
    float2 o;
    o.x = elu_f(accx * inv + b[c0 + 0]);
    o.y = elu_f(accy * inv + b[c0 + 1]);
    *reinterpret_cast<float2*>(out1 + (size_t)node * 128 + c0) = o;
}

// Layer 2: H=1, C=64. One wave per node; lane handles channel `lane` (bf16). +b2 fused.
__global__ __launch_bounds__(256) void agg2_kernel(const int* __restrict__ rp,
                                                   const int* __restrict__ cs,
                                                   const unsigned short* __restrict__ h2b,
                                                   const float* __restrict__ as,
                                                   const float* __restrict__ ad,
                                                   const float* __restrict__ b2,
                                                   float* __restrict__ out2) {
    int wid = threadIdx.x >> 6, lane = threadIdx.x & 63;
    int node = blockIdx.x * 4 + wid;
    if (node >= NN) return;
    float adv = ad[node];
    float acc = 0.f, wsum = 0.f;
    int beg = rp[node], end = rp[node + 1];

    int sA = cs[beg];
    int sB = (beg + 1 < end) ? cs[beg + 1] : 0;
    float asA = as[sA];
    unsigned short pA = h2b[(size_t)sA * 64 + lane];
    for (int j = beg; j < end; ++j) {
        int sC = (j + 2 < end) ? cs[j + 2] : 0;
        float asB = as[sB];
        unsigned short pB = h2b[(size_t)sB * 64 + lane];
        float e = asA + adv;
        e = e > 0.f ? e : NEG * e;
        float w = __expf(e);
        float hv = __uint_as_float(((unsigned int)pA) << 16);
        acc += w * hv; wsum += w;
        asA = asB; pA = pB; sB = sC;
    }
    out2[(size_t)node * 64 + lane] = acc / (wsum + 1e-16f) + b2[lane];
}

// ---------------- MLP head + mean pool (b2 already fused into out2) ----------------
__global__ __launch_bounds__(256) void mlp_pool_kernel(const float* __restrict__ out2,
                                                       const float* __restrict__ Wl1,
                                                       const float* __restrict__ bl1,
                                                       const float* __restrict__ Wl2,
                                                       const float* __restrict__ bl2,
                                                       float* __restrict__ pool) {
    __shared__ float sW1[64 * 64];
    __shared__ float sW2[64 * 64];
    __shared__ float sv[4][64];
    __shared__ float st[4][64];
    __shared__ float sacc[256];
    int tid = threadIdx.x;
    for (int i = tid; i < 64 * 64; i += 256) { sW1[i] = Wl1[i]; sW2[i] = Wl2[i]; }
    __syncthreads();
    int ln = tid / 64, c = tid % 64;
    float bl1c = bl1[c], bl2c = bl2[c];
    float acc = 0.f;
    for (int base = blockIdx.x * 4; base < NN; base += gridDim.x * 4) {
        int node = base + ln;
        float v = 0.f;
        if (node < NN) v = out2[(size_t)node * 64 + c];
        sv[ln][c] = v;
        __syncthreads();
        float t = bl1c;
#pragma unroll
        for (int k = 0; k < 64; ++k) t += sv[ln][k] * sW1[k * 64 + c];
        t = t > 0.f ? t : __expf(t) - 1.f;
        st[ln][c] = t;
        __syncthreads();
        float o = bl2c;
#pragma unroll
        for (int k = 0; k < 64; ++k) o += st[ln][k] * sW2[k * 64 + c];
        if (node < NN) acc += o;
        __syncthreads();
    }
    sacc[tid] = acc;
    __syncthreads();
    if (tid < 64) {
        float r = sacc[tid] + sacc[64 + tid] + sacc[128 + tid] + sacc[192 + tid];
        atomicAdd(&pool[tid], r);
    }
}

__global__ void finalize_kernel(const float* __restrict__ pool, float* __restrict__ out) {
    int c = threadIdx.x;
    if (c < 64) out[c] = pool[c] * (1.0f / NN);
}

extern "C" void kernel_launch(void* const* d_in, const int* in_sizes, int n_in,
                              void* d_out, int out_size, void* d_ws, size_t ws_size,
                              hipStream_t stream) {
    const float* x      = (const float*)d_in[0];
    const int*   ei     = (const int*)d_in[1];
    const float* W1     = (const float*)d_in[2];
    const float* a_src1 = (const float*)d_in[3];
    const float* a_dst1 = (const float*)d_in[4];
    const float* b1     = (const float*)d_in[5];
    const float* W2     = (const float*)d_in[6];
    const float* a_src2 = (const float*)d_in[7];
    const float* a_dst2 = (const float*)d_in[8];
    const float* b2     = (const float*)d_in[9];
    const float* Wl1    = (const float*)d_in[10];
    const float* bl1    = (const float*)d_in[11];
    const float* Wl2    = (const float*)d_in[12];
    const float* bl2    = (const float*)d_in[13];
    float* out = (float*)d_out;

    float* ws = (float*)d_ws;
    size_t o = 0;
    float* h1      = ws + o; o += (size_t)NN * 128;   // region A: h1 f32; later out2 + h2b
    float* out1    = ws + o; o += (size_t)NN * 128;   // region B
    float* h2      = ws + o; o += (size_t)NN * 64;    // region C: h1b (bf16) then h2 f32
    float* as1     = ws + o; o += NN * 2;
    float* ad1     = ws + o; o += NN * 2;
    float* as2     = ws + o; o += NN;
    float* ad2     = ws + o; o += NN;
    float* pool    = ws + o; o += 64;
    int* deg       = (int*)(ws + o); o += NN;
    int* row_ptr   = (int*)(ws + o); o += NN + 2;
    int* cursor    = (int*)(ws + o); o += NN;
    int* partials  = (int*)(ws + o); o += 128;
    int* csr_src   = (int*)(ws + o); o += EP;

    // Aliases (timeline-disjoint):
    unsigned short* h1b = (unsigned short*)h2;              // NN*128 bf16 = NN*64 f32, dead before gemm2 writes h2
    float* out2         = h1;                               // NN*64 f32, h1 f32 dead after alpha1
    unsigned short* h2b = (unsigned short*)(h1 + (size_t)NN * 64);  // NN*64 bf16 in A's 2nd half

    constexpr int SCAN_BLOCKS = (NN + 1023) / 1024;   // 98

    // ---- CSR build (shared by both layers) ----
    hipMemsetAsync(deg, 0, (size_t)NN * sizeof(int), stream);
    hipMemsetAsync(pool, 0, 64 * sizeof(float), stream);
    count_deg_kernel<<<(EP + 255) / 256, 256, 0, stream>>>(ei, deg);
    scan1_kernel<<<SCAN_BLOCKS, 256, 0, stream>>>(deg, row_ptr, partials);
    scan2_kernel<<<1, 64, 0, stream>>>(partials, SCAN_BLOCKS);
    scan3_kernel<<<(NN + 255) / 256, 256, 0, stream>>>(row_ptr, cursor, partials);
    scatter_kernel<<<(EP + 255) / 256, 256, 0, stream>>>(ei, cursor, csr_src);

    // ---- layer 1 ----
    gemm_tiled<256, 128, 128><<<(NN + 127) / 128, 256, 0, stream>>>(x, W1, h1, h1b);
    alpha_kernel<2, 64><<<(NN * 2 + 255) / 256, 256, 0, stream>>>(h1, a_src1, a_dst1, as1, ad1);
    agg1_kernel<<<(NN + 3) / 4, 256, 0, stream>>>(row_ptr, csr_src, h1b, as1, ad1, b1, out1);

    // ---- layer 2 ----
    gemm_tiled<128, 64, 256><<<(NN + 255) / 256, 256, 0, stream>>>(out1, W2, h2, h2b);
    alpha_kernel<1, 64><<<(NN + 255) / 256, 256, 0, stream>>>(h2, a_src2, a_dst2, as2, ad2);
    agg2_kernel<<<(NN + 3) / 4, 256, 0, stream>>>(row_ptr, csr_src, h2b, as2, ad2, b2, out2);

    // ---- MLP head + global mean pool ----
    mlp_pool_kernel<<<2048, 256, 0, stream>>>(out2, Wl1, bl1, Wl2, bl2, pool);
    finalize_kernel<<<1, 64, 0, stream>>>(pool, out);
}

// Round 15
// 748.280 us; speedup vs baseline: 7.2057x; 1.1051x over previous
//
#include <hip/hip_runtime.h>
#include <hip/hip_bf16.h>

constexpr int NN = 100000;            // nodes
constexpr int NE = 1600000;           // edges (without self loops)
constexpr int EP = NE + NN;           // edges incl. self loops
constexpr float NEG = 0.2f;           // leaky relu slope
constexpr int EPT = 4;                // edges per thread in CSR-build passes

__device__ __forceinline__ float elu_f(float x) { return x > 0.f ? x : __expf(x) - 1.f; }

__device__ __forceinline__ void f4fma(float4& a, float s, const float4& b) {
    a.x += s * b.x; a.y += s * b.y; a.z += s * b.z; a.w += s * b.w;
}

// round-to-nearest-even f32 -> bf16 (values are finite; no NaN handling needed)
__device__ __forceinline__ unsigned short bf16rne(float f) {
    unsigned int u = __float_as_uint(f);
    u += 0x7fffu + ((u >> 16) & 1u);
    return (unsigned short)(u >> 16);
}
__device__ __forceinline__ unsigned int pk2(float lo, float hi) {
    return (unsigned int)bf16rne(lo) | ((unsigned int)bf16rne(hi) << 16);
}

// ---------------- LDS-tiled GEMM: H[N,M] = X[N,K] @ W[K,M]; also writes bf16 copy Hb ----------------
template<int K, int M, int BN>
__global__ __launch_bounds__(256) void gemm_tiled(const float* __restrict__ X,
                                                  const float* __restrict__ W,
                                                  float* __restrict__ H,
                                                  unsigned short* __restrict__ Hb) {
    constexpr int KT = 32;
    constexpr int CG = M / 8;           // col groups of 8
    constexpr int NG = 256 / CG;        // node groups of 8
    static_assert(NG * 8 == BN, "BN must equal 8*256/CG");
    __shared__ float Xs[KT * BN];
    __shared__ float Ws[KT * M];
    int tid = threadIdx.x;
    int cg = tid % CG, ng = tid / CG;
    int n0 = ng * 8, c0 = cg * 8;
    int nodeBase = blockIdx.x * BN;

    float4 acc[8][2];
#pragma unroll
    for (int i = 0; i < 8; ++i) {
        acc[i][0] = make_float4(0.f, 0.f, 0.f, 0.f);
        acc[i][1] = make_float4(0.f, 0.f, 0.f, 0.f);
    }

    for (int k0 = 0; k0 < K; k0 += KT) {
#pragma unroll
        for (int r = 0; r < BN / 32; ++r) {
            int ln = tid / 8 + 32 * r;
            int kk = (tid % 8) * 4;
            int node = nodeBase + ln;
            node = node < NN ? node : NN - 1;
            float4 v = *reinterpret_cast<const float4*>(X + (size_t)node * K + k0 + kk);
            Xs[(kk + 0) * BN + ln] = v.x;
            Xs[(kk + 1) * BN + ln] = v.y;
            Xs[(kk + 2) * BN + ln] = v.z;
            Xs[(kk + 3) * BN + ln] = v.w;
        }
#pragma unroll
        for (int r = 0; r < (KT * M) / 1024; ++r) {
            int f = tid + 256 * r;
            *reinterpret_cast<float4*>(Ws + 4 * f) =
                *reinterpret_cast<const float4*>(W + (size_t)k0 * M + 4 * f);
        }
        __syncthreads();
#pragma unroll
        for (int k = 0; k < KT; ++k) {
            const float4 xa = *reinterpret_cast<const float4*>(Xs + k * BN + n0);
            const float4 xb = *reinterpret_cast<const float4*>(Xs + k * BN + n0 + 4);
            const float4 wa = *reinterpret_cast<const float4*>(Ws + k * M + c0);
            const float4 wb = *reinterpret_cast<const float4*>(Ws + k * M + c0 + 4);
            f4fma(acc[0][0], xa.x, wa); f4fma(acc[0][1], xa.x, wb);
            f4fma(acc[1][0], xa.y, wa); f4fma(acc[1][1], xa.y, wb);
            f4fma(acc[2][0], xa.z, wa); f4fma(acc[2][1], xa.z, wb);
            f4fma(acc[3][0], xa.w, wa); f4fma(acc[3][1], xa.w, wb);
            f4fma(acc[4][0], xb.x, wa); f4fma(acc[4][1], xb.x, wb);
            f4fma(acc[5][0], xb.y, wa); f4fma(acc[5][1], xb.y, wb);
            f4fma(acc[6][0], xb.z, wa); f4fma(acc[6][1], xb.z, wb);
            f4fma(acc[7][0], xb.w, wa); f4fma(acc[7][1], xb.w, wb);
        }
        __syncthreads();
    }
#pragma unroll
    for (int i = 0; i < 8; ++i) {
        int node = nodeBase + n0 + i;
        if (node < NN) {
            *reinterpret_cast<float4*>(H + (size_t)node * M + c0)     = acc[i][0];
            *reinterpret_cast<float4*>(H + (size_t)node * M + c0 + 4) = acc[i][1];
            uint4 p;
            p.x = pk2(acc[i][0].x, acc[i][0].y);
            p.y = pk2(acc[i][0].z, acc[i][0].w);
            p.z = pk2(acc[i][1].x, acc[i][1].y);
            p.w = pk2(acc[i][1].z, acc[i][1].w);
            *reinterpret_cast<uint4*>(Hb + (size_t)node * M + c0) = p;
        }
    }
}

// ---------------- per-node attention coefficients ----------------
template<int H, int C>
__global__ void alpha_kernel(const float* __restrict__ Hm, const float* __restrict__ a_src,
                             const float* __restrict__ a_dst,
                             float* __restrict__ as, float* __restrict__ ad) {
    int idx = blockIdx.x * blockDim.x + threadIdx.x;   // node*H + h
    if (idx >= NN * H) return;
    int node = idx / H, h = idx % H;
    const float* hr = Hm + (size_t)node * (H * C) + h * C;
    const float* sr = a_src + h * C;
    const float* dr = a_dst + h * C;
    float s = 0.f, d = 0.f;
#pragma unroll
    for (int c = 0; c < C; c += 4) {
        float4 hv = *reinterpret_cast<const float4*>(hr + c);
        float4 sv = *reinterpret_cast<const float4*>(sr + c);
        float4 dv = *reinterpret_cast<const float4*>(dr + c);
        s += hv.x * sv.x + hv.y * sv.y + hv.z * sv.z + hv.w * sv.w;
        d += hv.x * dv.x + hv.y * dv.y + hv.z * dv.z + hv.w * dv.w;
    }
    as[idx] = s; ad[idx] = d;
}

// ================= CSR build (by destination) =================
// Pass 1: deg histogram + per-edge rank via atomic return value. 4 edges/thread (ILP).
__global__ __launch_bounds__(256) void count_rank_kernel(const int* __restrict__ ei,
                                                         int* __restrict__ deg,
                                                         int* __restrict__ rank) {
    int base = blockIdx.x * (256 * EPT) + threadIdx.x;
    int d[EPT];
#pragma unroll
    for (int e = 0; e < EPT; ++e) {
        int i = base + e * 256;
        if (i < EP) d[e] = (i < NE) ? ei[NE + i] : (i - NE);
    }
    int pos[EPT];
#pragma unroll
    for (int e = 0; e < EPT; ++e) {
        int i = base + e * 256;
        if (i < EP) pos[e] = atomicAdd(&deg[d[e]], 1);
    }
#pragma unroll
    for (int e = 0; e < EPT; ++e) {
        int i = base + e * 256;
        if (i < EP) rank[i] = pos[e];
    }
}

__global__ __launch_bounds__(256) void scan1_kernel(const int* __restrict__ deg,
                                                    int* __restrict__ excl,
                                                    int* __restrict__ partials) {
    __shared__ int ts[256];
    int tid = threadIdx.x;
    int idx0 = blockIdx.x * 1024 + tid * 4;
    int v0 = (idx0 + 0 < NN) ? deg[idx0 + 0] : 0;
    int v1 = (idx0 + 1 < NN) ? deg[idx0 + 1] : 0;
    int v2 = (idx0 + 2 < NN) ? deg[idx0 + 2] : 0;
    int v3 = (idx0 + 3 < NN) ? deg[idx0 + 3] : 0;
    int s0 = v0, s1 = s0 + v1, s2 = s1 + v2, s3 = s2 + v3;
    ts[tid] = s3;
    __syncthreads();
    for (int off = 1; off < 256; off <<= 1) {
        int t = (tid >= off) ? ts[tid - off] : 0;
        __syncthreads();
        ts[tid] += t;
        __syncthreads();
    }
    int te = ts[tid] - s3;
    if (idx0 + 0 < NN) excl[idx0 + 0] = te;
    if (idx0 + 1 < NN) excl[idx0 + 1] = te + s0;
    if (idx0 + 2 < NN) excl[idx0 + 2] = te + s1;
    if (idx0 + 3 < NN) excl[idx0 + 3] = te + s2;
    if (tid == 255) partials[blockIdx.x] = ts[255];
}

__global__ void scan2_kernel(int* __restrict__ partials, int nb) {
    if (threadIdx.x == 0 && blockIdx.x == 0) {
        int run = 0;
        for (int i = 0; i < nb; ++i) { int t = partials[i]; partials[i] = run; run += t; }
    }
}

__global__ void scan3_kernel(int* __restrict__ row_ptr, const int* __restrict__ partials) {
    int i = blockIdx.x * blockDim.x + threadIdx.x;
    if (i == 0) row_ptr[NN] = EP;
    if (i >= NN) return;
    row_ptr[i] += partials[i >> 10];
}

// Pass 2: atomic-free scatter: csr_src[row_ptr[d] + rank[i]] = s. 4 edges/thread.
__global__ __launch_bounds__(256) void scatter2_kernel(const int* __restrict__ ei,
                                                       const int* __restrict__ rank,
                                                       const int* __restrict__ row_ptr,
                                                       int* __restrict__ csr_src) {
    int base = blockIdx.x * (256 * EPT) + threadIdx.x;
#pragma unroll
    for (int e = 0; e < EPT; ++e) {
        int i = base + e * 256;
        if (i >= EP) continue;
        int s, d;
        if (i < NE) { s = ei[i]; d = ei[NE + i]; }
        else        { s = d = i - NE; }
        csr_src[row_ptr[d] + rank[i]] = s;
    }
}

// ================= gather aggregation (no atomics, software-pipelined, bf16 gather) =================
// Layer 1: H=2, C=64. One wave per node; lane handles channels 2*lane, 2*lane+1 (bf16-packed dword).
__global__ __launch_bounds__(256) void agg1_kernel(const int* __restrict__ rp,
                                                   const int* __restrict__ cs,
                                                   const unsigned short* __restrict__ h1b,
                                                   const float* __restrict__ as,
                                                   const float* __restrict__ ad,
                                                   const float* __restrict__ b,
                                                   float* __restrict__ out1) {
    int wid = threadIdx.x >> 6, lane = threadIdx.x & 63;
    int node = blockIdx.x * 4 + wid;
    if (node >= NN) return;
    int h = lane >> 5;
    int c0 = 2 * lane;
    float adv = ad[2 * node + h];
    float accx = 0.f, accy = 0.f, wsum = 0.f;
    int beg = rp[node], end = rp[node + 1];

    int sA = cs[beg];                                  // deg >= 1 always (self-loop)
    int sB = (beg + 1 < end) ? cs[beg + 1] : 0;
    float2 asA = *reinterpret_cast<const float2*>(as + 2 * sA);
    unsigned int pA = *reinterpret_cast<const unsigned int*>(h1b + (size_t)sA * 128 + c0);
    for (int j = beg; j < end; ++j) {
        int sC = (j + 2 < end) ? cs[j + 2] : 0;        // index for j+2
        float2 asB = *reinterpret_cast<const float2*>(as + 2 * sB);            // data j+1
        unsigned int pB = *reinterpret_cast<const unsigned int*>(h1b + (size_t)sB * 128 + c0);
        float e = (h ? asA.y : asA.x) + adv;           // compute j
        e = e > 0.f ? e : NEG * e;
        float w = __expf(e);
        float hx = __uint_as_float(pA << 16);          // channel c0
        float hy = __uint_as_float(pA & 0xffff0000u);  // channel c0+1
        accx += w * hx; accy += w * hy; wsum += w;
        asA = asB; pA = pB; sB = sC;                   // rotate
    }
    float inv = 1.f / (wsum + 1e-16f);
    float2 o;
    o.x = elu_f(accx * inv + b[c0 + 0]);
    o.y = elu_f(accy * inv + b[c0 + 1]);
    *reinterpret_cast<float2*>(out1 + (size_t)node * 128 + c0) = o;
}

// Layer 2: H=1, C=64. One wave per node; lane handles channel `lane` (bf16). +b2 fused.
__global__ __launch_bounds__(256) void agg2_kernel(const int* __restrict__ rp,
                                                   const int* __restrict__ cs,
                                                   const unsigned short* __restrict__ h2b,
                                                   const float* __restrict__ as,
                                                   const float* __restrict__ ad,
                                                   const float* __restrict__ b2,
                                                   float* __restrict__ out2) {
    int wid = threadIdx.x >> 6, lane = threadIdx.x & 63;
    int node = blockIdx.x * 4 + wid;
    if (node >= NN) return;
    float adv = ad[node];
    float acc = 0.f, wsum = 0.f;
    int beg = rp[node], end = rp[node + 1];

    int sA = cs[beg];
    int sB = (beg + 1 < end) ? cs[beg + 1] : 0;
    float asA = as[sA];
    unsigned short pA = h2b[(size_t)sA * 64 + lane];
    for (int j = beg; j < end; ++j) {
        int sC = (j + 2 < end) ? cs[j + 2] : 0;
        float asB = as[sB];
        unsigned short pB = h2b[(size_t)sB * 64 + lane];
        float e = asA + adv;
        e = e > 0.f ? e : NEG * e;
        float w = __expf(e);
        float hv = __uint_as_float(((unsigned int)pA) << 16);
        acc += w * hv; wsum += w;
        asA = asB; pA = pB; sB = sC;
    }
    out2[(size_t)node * 64 + lane] = acc / (wsum + 1e-16f) + b2[lane];
}

// ---------------- MLP head + mean pool (b2 already fused into out2) ----------------
__global__ __launch_bounds__(256) void mlp_pool_kernel(const float* __restrict__ out2,
                                                       const float* __restrict__ Wl1,
                                                       const float* __restrict__ bl1,
                                                       const float* __restrict__ Wl2,
                                                       const float* __restrict__ bl2,
                                                       float* __restrict__ pool) {
    __shared__ float sW1[64 * 64];
    __shared__ float sW2[64 * 64];
    __shared__ float sv[4][64];
    __shared__ float st[4][64];
    __shared__ float sacc[256];
    int tid = threadIdx.x;
    for (int i = tid; i < 64 * 64; i += 256) { sW1[i] = Wl1[i]; sW2[i] = Wl2[i]; }
    __syncthreads();
    int ln = tid / 64, c = tid % 64;
    float bl1c = bl1[c], bl2c = bl2[c];
    float acc = 0.f;
    for (int base = blockIdx.x * 4; base < NN; base += gridDim.x * 4) {
        int node = base + ln;
        float v = 0.f;
        if (node < NN) v = out2[(size_t)node * 64 + c];
        sv[ln][c] = v;
        __syncthreads();
        float t = bl1c;
#pragma unroll
        for (int k = 0; k < 64; ++k) t += sv[ln][k] * sW1[k * 64 + c];
        t = t > 0.f ? t : __expf(t) - 1.f;
        st[ln][c] = t;
        __syncthreads();
        float o = bl2c;
#pragma unroll
        for (int k = 0; k < 64; ++k) o += st[ln][k] * sW2[k * 64 + c];
        if (node < NN) acc += o;
        __syncthreads();
    }
    sacc[tid] = acc;
    __syncthreads();
    if (tid < 64) {
        float r = sacc[tid] + sacc[64 + tid] + sacc[128 + tid] + sacc[192 + tid];
        atomicAdd(&pool[tid], r);
    }
}

__global__ void finalize_kernel(const float* __restrict__ pool, float* __restrict__ out) {
    int c = threadIdx.x;
    if (c < 64) out[c] = pool[c] * (1.0f / NN);
}

extern "C" void kernel_launch(void* const* d_in, const int* in_sizes, int n_in,
                              void* d_out, int out_size, void* d_ws, size_t ws_size,
                              hipStream_t stream) {
    const float* x      = (const float*)d_in[0];
    const int*   ei     = (const int*)d_in[1];
    const float* W1     = (const float*)d_in[2];
    const float* a_src1 = (const float*)d_in[3];
    const float* a_dst1 = (const float*)d_in[4];
    const float* b1     = (const float*)d_in[5];
    const float* W2     = (const float*)d_in[6];
    const float* a_src2 = (const float*)d_in[7];
    const float* a_dst2 = (const float*)d_in[8];
    const float* b2     = (const float*)d_in[9];
    const float* Wl1    = (const float*)d_in[10];
    const float* bl1    = (const float*)d_in[11];
    const float* Wl2    = (const float*)d_in[12];
    const float* bl2    = (const float*)d_in[13];
    float* out = (float*)d_out;

    float* ws = (float*)d_ws;
    size_t o = 0;
    float* h1      = ws + o; o += (size_t)NN * 128;   // region A: h1 f32; later out2 + h2b
    float* out1    = ws + o; o += (size_t)NN * 128;   // region B
    float* h2      = ws + o; o += (size_t)NN * 64;    // region C: h1b (bf16) then h2 f32
    float* as1     = ws + o; o += NN * 2;
    float* ad1     = ws + o; o += NN * 2;
    float* as2     = ws + o; o += NN;
    float* ad2     = ws + o; o += NN;
    float* pool    = ws + o; o += 64;
    int* deg       = (int*)(ws + o); o += NN;
    int* row_ptr   = (int*)(ws + o); o += NN + 2;
    int* rank      = (int*)(ws + o); o += EP;
    int* partials  = (int*)(ws + o); o += 128;
    int* csr_src   = (int*)(ws + o); o += EP;

    // Aliases (timeline-disjoint):
    unsigned short* h1b = (unsigned short*)h2;              // NN*128 bf16 = NN*64 f32, dead before gemm2 writes h2
    float* out2         = h1;                               // NN*64 f32, h1 f32 dead after alpha1
    unsigned short* h2b = (unsigned short*)(h1 + (size_t)NN * 64);  // NN*64 bf16 in A's 2nd half

    constexpr int SCAN_BLOCKS = (NN + 1023) / 1024;   // 98
    constexpr int EDGE_BLOCKS = (EP + 256 * EPT - 1) / (256 * EPT);

    // ---- CSR build (shared by both layers) ----
    hipMemsetAsync(deg, 0, (size_t)NN * sizeof(int), stream);
    hipMemsetAsync(pool, 0, 64 * sizeof(float), stream);
    count_rank_kernel<<<EDGE_BLOCKS, 256, 0, stream>>>(ei, deg, rank);
    scan1_kernel<<<SCAN_BLOCKS, 256, 0, stream>>>(deg, row_ptr, partials);
    scan2_kernel<<<1, 64, 0, stream>>>(partials, SCAN_BLOCKS);
    scan3_kernel<<<(NN + 255) / 256, 256, 0, stream>>>(row_ptr, partials);
    scatter2_kernel<<<EDGE_BLOCKS, 256, 0, stream>>>(ei, rank, row_ptr, csr_src);

    // ---- layer 1 ----
    gemm_tiled<256, 128, 128><<<(NN + 127) / 128, 256, 0, stream>>>(x, W1, h1, h1b);
    alpha_kernel<2, 64><<<(NN * 2 + 255) / 256, 256, 0, stream>>>(h1, a_src1, a_dst1, as1, ad1);
    agg1_kernel<<<(NN + 3) / 4, 256, 0, stream>>>(row_ptr, csr_src, h1b, as1, ad1, b1, out1);

    // ---- layer 2 ----
    gemm_tiled<128, 64, 256><<<(NN + 255) / 256, 256, 0, stream>>>(out1, W2, h2, h2b);
    alpha_kernel<1, 64><<<(NN + 255) / 256, 256, 0, stream>>>(h2, a_src2, a_dst2, as2, ad2);
    agg2_kernel<<<(NN + 3) / 4, 256, 0, stream>>>(row_ptr, csr_src, h2b, as2, ad2, b2, out2);

    // ---- MLP head + global mean pool ----
    mlp_pool_kernel<<<2048, 256, 0, stream>>>(out2, Wl1, bl1, Wl2, bl2, pool);
    finalize_kernel<<<1, 64, 0, stream>>>(pool, out);
}